// Round 1
// baseline (2454.244 us; speedup 1.0000x reference)
//
#include <hip/hip_runtime.h>
#include <cstddef>

#define EMB 1024
#define NH 16
#define HD 64
#define BATCH 4
#define SEQ 2048
#define MROWS (BATCH * SEQ)   // 8192

// ---------------------------------------------------------------------------
// Shared GEMM main loop: C[128,128] tile of A[M,1024] @ W[N,1024]^T
// 256 threads, BK=16, each thread owns an 8x8 micro-tile split as
// rows {ty*4+i, ty*4+64+i}, cols {tx*4+j, tx*4+64+j}.
// ---------------------------------------------------------------------------
__device__ __forceinline__ void gemm_mainloop(const float* __restrict__ A,
                                              const float* __restrict__ Wt,
                                              float (*As)[132], float (*Bs)[132],
                                              int m0, int n0, int t,
                                              float acc[8][8]) {
    const int K = 1024;
    const int tx = t & 15, ty = t >> 4;

    // global->LDS staging indices: 512 float4 per operand tile, 2 per thread
    const int vid0 = t, vid1 = t + 256;
    const int ar0 = vid0 >> 2, ac0 = (vid0 & 3) << 2;
    const int ar1 = vid1 >> 2, ac1 = (vid1 & 3) << 2;

    float4 pa0, pa1, pb0, pb1;

    auto loadT = [&](int kt) {
        pa0 = *(const float4*)(A + (size_t)(m0 + ar0) * K + kt + ac0);
        pa1 = *(const float4*)(A + (size_t)(m0 + ar1) * K + kt + ac1);
        pb0 = *(const float4*)(Wt + (size_t)(n0 + ar0) * K + kt + ac0);
        pb1 = *(const float4*)(Wt + (size_t)(n0 + ar1) * K + kt + ac1);
    };
    auto storeT = [&]() {
        As[ac0 + 0][ar0] = pa0.x; As[ac0 + 1][ar0] = pa0.y;
        As[ac0 + 2][ar0] = pa0.z; As[ac0 + 3][ar0] = pa0.w;
        As[ac1 + 0][ar1] = pa1.x; As[ac1 + 1][ar1] = pa1.y;
        As[ac1 + 2][ar1] = pa1.z; As[ac1 + 3][ar1] = pa1.w;
        Bs[ac0 + 0][ar0] = pb0.x; Bs[ac0 + 1][ar0] = pb0.y;
        Bs[ac0 + 2][ar0] = pb0.z; Bs[ac0 + 3][ar0] = pb0.w;
        Bs[ac1 + 0][ar1] = pb1.x; Bs[ac1 + 1][ar1] = pb1.y;
        Bs[ac1 + 2][ar1] = pb1.z; Bs[ac1 + 3][ar1] = pb1.w;
    };

    loadT(0);
    storeT();
    __syncthreads();

    for (int kt = 16; kt <= K; kt += 16) {
        const bool more = (kt < K);
        if (more) loadT(kt);   // prefetch next tile; latency hides under compute
#pragma unroll
        for (int k = 0; k < 16; ++k) {
            float a[8], b[8];
            *(float4*)&a[0] = *(const float4*)&As[k][ty * 4];
            *(float4*)&a[4] = *(const float4*)&As[k][ty * 4 + 64];
            *(float4*)&b[0] = *(const float4*)&Bs[k][tx * 4];
            *(float4*)&b[4] = *(const float4*)&Bs[k][tx * 4 + 64];
#pragma unroll
            for (int i = 0; i < 8; ++i)
#pragma unroll
                for (int j = 0; j < 8; ++j)
                    acc[i][j] = fmaf(a[i], b[j], acc[i][j]);
        }
        __syncthreads();
        if (more) storeT();
        __syncthreads();
    }
}

// ---------------------------------------------------------------------------
// Kernel 1: kqv = x @ W_kqv^T + b_kqv, scattered into K/Q/V [B,H,S,D]
// split order (per reference): k, q, v
// ---------------------------------------------------------------------------
__global__ __launch_bounds__(256) void gemm_kqv_kernel(
    const float* __restrict__ X, const float* __restrict__ W,
    const float* __restrict__ bias, float* __restrict__ Ko,
    float* __restrict__ Qo, float* __restrict__ Vo) {
    __shared__ float As[16][132];
    __shared__ float Bs[16][132];
    float acc[8][8];
#pragma unroll
    for (int i = 0; i < 8; ++i)
#pragma unroll
        for (int j = 0; j < 8; ++j) acc[i][j] = 0.f;

    const int m0 = blockIdx.x * 128, n0 = blockIdx.y * 128;
    const int t = threadIdx.x;
    gemm_mainloop(X, W, As, Bs, m0, n0, t, acc);

    const int tx = t & 15, ty = t >> 4;
    const int which = n0 >> 10;   // tile never crosses a 1024 boundary
    float* outp = (which == 0) ? Ko : ((which == 1) ? Qo : Vo);

#pragma unroll
    for (int jh = 0; jh < 2; ++jh) {
        const int colbase = n0 + tx * 4 + jh * 64;   // [0,3072)
        const int cm = colbase & 1023;
        const int h = cm >> 6;
        const int d0 = cm & 63;                      // thread's 4 cols stay in one head
        float4 bb;
        bb.x = bias[colbase + 0]; bb.y = bias[colbase + 1];
        bb.z = bias[colbase + 2]; bb.w = bias[colbase + 3];
#pragma unroll
        for (int ih = 0; ih < 2; ++ih)
#pragma unroll
            for (int i = 0; i < 4; ++i) {
                const int row = m0 + ty * 4 + ih * 64 + i;   // [0,8192)
                const int bidx = row >> 11, s = row & 2047;
                float4 v;
                v.x = acc[ih * 4 + i][jh * 4 + 0] + bb.x;
                v.y = acc[ih * 4 + i][jh * 4 + 1] + bb.y;
                v.z = acc[ih * 4 + i][jh * 4 + 2] + bb.z;
                v.w = acc[ih * 4 + i][jh * 4 + 3] + bb.w;
                *(float4*)(outp + (((size_t)(bidx * NH + h) * SEQ + s) << 6) + d0) = v;
            }
    }
}

// ---------------------------------------------------------------------------
// Kernel 3: out = Y @ W_proj^T + b_proj   (plain row-major epilogue)
// ---------------------------------------------------------------------------
__global__ __launch_bounds__(256) void gemm_proj_kernel(
    const float* __restrict__ Y, const float* __restrict__ W,
    const float* __restrict__ bias, float* __restrict__ Out) {
    __shared__ float As[16][132];
    __shared__ float Bs[16][132];
    float acc[8][8];
#pragma unroll
    for (int i = 0; i < 8; ++i)
#pragma unroll
        for (int j = 0; j < 8; ++j) acc[i][j] = 0.f;

    const int m0 = blockIdx.x * 128, n0 = blockIdx.y * 128;
    const int t = threadIdx.x;
    gemm_mainloop(Y, W, As, Bs, m0, n0, t, acc);

    const int tx = t & 15, ty = t >> 4;
#pragma unroll
    for (int jh = 0; jh < 2; ++jh) {
        const int col = n0 + tx * 4 + jh * 64;
        float4 bb;
        bb.x = bias[col + 0]; bb.y = bias[col + 1];
        bb.z = bias[col + 2]; bb.w = bias[col + 3];
#pragma unroll
        for (int ih = 0; ih < 2; ++ih)
#pragma unroll
            for (int i = 0; i < 4; ++i) {
                const int row = m0 + ty * 4 + ih * 64 + i;
                float4 v;
                v.x = acc[ih * 4 + i][jh * 4 + 0] + bb.x;
                v.y = acc[ih * 4 + i][jh * 4 + 1] + bb.y;
                v.z = acc[ih * 4 + i][jh * 4 + 2] + bb.z;
                v.w = acc[ih * 4 + i][jh * 4 + 3] + bb.w;
                *(float4*)(Out + (size_t)row * EMB + col) = v;
            }
    }
}

// ---------------------------------------------------------------------------
// Kernel 2: causal flash attention, fp32.
// Grid: (S/64 q-tiles, B*H). 256 threads = 16x16 (tx,ty).
// S-phase: thread covers q-rows {ty*4+i}, k-cols {tx+16u} (interleaved,
// conflict-free). PV-phase: d-cols {tx*4+j} (blocked, float4-friendly).
// ---------------------------------------------------------------------------
__global__ __launch_bounds__(256) void attn_kernel(
    const float* __restrict__ Kt, const float* __restrict__ Qt,
    const float* __restrict__ Vt, float* __restrict__ Y) {
    __shared__ float Qs[64][68];
    __shared__ float Ks[64][68];
    __shared__ float Vs[64][68];
    __shared__ float Ps[64][68];

    const int qt = blockIdx.x;          // 0..31
    const int bh = blockIdx.y;          // 0..63
    const int bidx = bh >> 4, h = bh & 15;
    const float* Qp = Qt + ((size_t)bh * SEQ << 6);
    const float* Kp = Kt + ((size_t)bh * SEQ << 6);
    const float* Vp = Vt + ((size_t)bh * SEQ << 6);

    const int t = threadIdx.x, tx = t & 15, ty = t >> 4;

    // load Q tile once
#pragma unroll
    for (int i = 0; i < 4; ++i) {
        const int vid = t + (i << 8);
        const int r = vid >> 4, c = (vid & 15) << 2;
        *(float4*)&Qs[r][c] =
            *(const float4*)(Qp + (((size_t)(qt * 64 + r)) << 6) + c);
    }

    float m_i[4], l_i[4], o[4][4];
#pragma unroll
    for (int i = 0; i < 4; ++i) {
        m_i[i] = -1e30f; l_i[i] = 0.f;
#pragma unroll
        for (int j = 0; j < 4; ++j) o[i][j] = 0.f;
    }

    float4 kv[8];
    auto loadKV = [&](int tile) {
        const float* kp = Kp + ((size_t)(tile * 64) << 6);
        const float* vp = Vp + ((size_t)(tile * 64) << 6);
#pragma unroll
        for (int i = 0; i < 4; ++i) {
            const int vid = t + (i << 8);
            const int r = vid >> 4, c = (vid & 15) << 2;
            kv[i] = *(const float4*)(kp + (r << 6) + c);
            kv[4 + i] = *(const float4*)(vp + (r << 6) + c);
        }
    };

    loadKV(0);
    const int ntiles = qt + 1;
    for (int tile = 0; tile < ntiles; ++tile) {
        __syncthreads();   // prev iteration's LDS reads done
#pragma unroll
        for (int i = 0; i < 4; ++i) {
            const int vid = t + (i << 8);
            const int r = vid >> 4, c = (vid & 15) << 2;
            *(float4*)&Ks[r][c] = kv[i];
            *(float4*)&Vs[r][c] = kv[4 + i];
        }
        if (tile + 1 < ntiles) loadKV(tile + 1);   // prefetch next K/V
        __syncthreads();

        // ---- S = scale * Q K^T (+ causal mask) ----
        float sacc[4][4];
#pragma unroll
        for (int i = 0; i < 4; ++i)
#pragma unroll
            for (int u = 0; u < 4; ++u) sacc[i][u] = 0.f;

#pragma unroll
        for (int k4 = 0; k4 < 16; ++k4) {
            float4 qv[4], kk[4];
#pragma unroll
            for (int i = 0; i < 4; ++i)
                qv[i] = *(const float4*)&Qs[ty * 4 + i][k4 * 4];
#pragma unroll
            for (int u = 0; u < 4; ++u)
                kk[u] = *(const float4*)&Ks[tx + 16 * u][k4 * 4];
#pragma unroll
            for (int i = 0; i < 4; ++i)
#pragma unroll
                for (int u = 0; u < 4; ++u) {
                    sacc[i][u] = fmaf(qv[i].x, kk[u].x, sacc[i][u]);
                    sacc[i][u] = fmaf(qv[i].y, kk[u].y, sacc[i][u]);
                    sacc[i][u] = fmaf(qv[i].z, kk[u].z, sacc[i][u]);
                    sacc[i][u] = fmaf(qv[i].w, kk[u].w, sacc[i][u]);
                }
        }

        const bool diag = (tile == qt);
#pragma unroll
        for (int i = 0; i < 4; ++i)
#pragma unroll
            for (int u = 0; u < 4; ++u) {
                float v = sacc[i][u] * 0.125f;
                if (diag) {
                    const int qi = qt * 64 + ty * 4 + i;
                    const int kj = tile * 64 + tx + 16 * u;
                    if (kj > qi) v = -1e30f;
                }
                sacc[i][u] = v;
            }

        // ---- online softmax ----
        float alpha[4];
#pragma unroll
        for (int i = 0; i < 4; ++i) {
            float rm = fmaxf(fmaxf(sacc[i][0], sacc[i][1]),
                             fmaxf(sacc[i][2], sacc[i][3]));
#pragma unroll
            for (int msk = 1; msk < 16; msk <<= 1)
                rm = fmaxf(rm, __shfl_xor(rm, msk, 16));
            const float mnew = fmaxf(m_i[i], rm);
            alpha[i] = __expf(m_i[i] - mnew);
            m_i[i] = mnew;
        }
#pragma unroll
        for (int i = 0; i < 4; ++i) {
            float sum = 0.f;
#pragma unroll
            for (int u = 0; u < 4; ++u) {
                const float p = __expf(sacc[i][u] - m_i[i]);
                sacc[i][u] = p;
                sum += p;
            }
#pragma unroll
            for (int msk = 1; msk < 16; msk <<= 1)
                sum += __shfl_xor(sum, msk, 16);
            l_i[i] = alpha[i] * l_i[i] + sum;
#pragma unroll
            for (int j = 0; j < 4; ++j) o[i][j] *= alpha[i];
        }

        // ---- stage P, then PV ----
#pragma unroll
        for (int i = 0; i < 4; ++i)
#pragma unroll
            for (int u = 0; u < 4; ++u)
                Ps[ty * 4 + i][tx + 16 * u] = sacc[i][u];
        __syncthreads();

#pragma unroll
        for (int k4 = 0; k4 < 16; ++k4) {
            float4 pp[4], vv[4];
#pragma unroll
            for (int i = 0; i < 4; ++i)
                pp[i] = *(const float4*)&Ps[ty * 4 + i][k4 * 4];
#pragma unroll
            for (int c = 0; c < 4; ++c)
                vv[c] = *(const float4*)&Vs[k4 * 4 + c][tx * 4];
#pragma unroll
            for (int i = 0; i < 4; ++i)
#pragma unroll
                for (int c = 0; c < 4; ++c) {
                    const float p = (&pp[i].x)[c];
                    o[i][0] = fmaf(p, vv[c].x, o[i][0]);
                    o[i][1] = fmaf(p, vv[c].y, o[i][1]);
                    o[i][2] = fmaf(p, vv[c].z, o[i][2]);
                    o[i][3] = fmaf(p, vv[c].w, o[i][3]);
                }
        }
    }

    // epilogue: O /= l, write to Y[B,S,E]
#pragma unroll
    for (int i = 0; i < 4; ++i) {
        const float inv = 1.0f / l_i[i];
        const int qg = qt * 64 + ty * 4 + i;
        float4 v;
        v.x = o[i][0] * inv; v.y = o[i][1] * inv;
        v.z = o[i][2] * inv; v.w = o[i][3] * inv;
        *(float4*)(Y + ((size_t)(bidx * SEQ + qg) * EMB) + (h << 6) + tx * 4) = v;
    }
}

// ---------------------------------------------------------------------------
extern "C" void kernel_launch(void* const* d_in, const int* in_sizes, int n_in,
                              void* d_out, int out_size, void* d_ws, size_t ws_size,
                              hipStream_t stream) {
    const float* x  = (const float*)d_in[0];
    const float* Wk = (const float*)d_in[1];
    const float* bk = (const float*)d_in[2];
    const float* Wp = (const float*)d_in[3];
    const float* bp = (const float*)d_in[4];
    float* out = (float*)d_out;

    const size_t per = (size_t)BATCH * NH * SEQ * HD;   // 8388608 floats
    float* Ko = (float*)d_ws;
    float* Qo = Ko + per;
    float* Vo = Qo + per;
    float* Yo = Vo + per;   // total ws use: 4 * 32 MiB = 128 MiB

    gemm_kqv_kernel<<<dim3(MROWS / 128, 3072 / 128), 256, 0, stream>>>(
        x, Wk, bk, Ko, Qo, Vo);
    attn_kernel<<<dim3(SEQ / 64, BATCH * NH), 256, 0, stream>>>(Ko, Qo, Vo, Yo);
    gemm_proj_kernel<<<dim3(MROWS / 128, EMB / 128), 256, 0, stream>>>(
        Yo, Wp, bp, out);
}

// Round 2
// 634.156 us; speedup vs baseline: 3.8701x; 3.8701x over previous
//
#include <hip/hip_runtime.h>
#include <cstddef>
#include <cstdint>

#define EMB 1024
#define NH 16
#define HD 64
#define BATCH 4
#define SEQ 2048
#define MROWS (BATCH * SEQ)   // 8192

typedef __attribute__((ext_vector_type(8))) short bf16x8;   // 8 bf16 in 4 VGPRs
typedef __attribute__((ext_vector_type(4))) float f32x4;    // MFMA C/D

__device__ __forceinline__ float bf2f(unsigned short u) {
    union { unsigned int i; float f; } c; c.i = ((unsigned int)u) << 16; return c.f;
}
__device__ __forceinline__ unsigned short f2bf(float f) {   // RNE
    union { float f; unsigned int i; } c; c.f = f;
    return (unsigned short)((c.i + 0x7FFFu + ((c.i >> 16) & 1u)) >> 16);
}

// async global->LDS, 16B per lane. LDS dest must be wave-uniform base; HW adds lane*16.
#define GLOAD_LDS16(gp, lp) __builtin_amdgcn_global_load_lds(                  \
    (const __attribute__((address_space(1))) void*)(gp),                       \
    (__attribute__((address_space(3))) void*)(lp), 16, 0, 0)

// ---------------------------------------------------------------------------
// fp32 -> bf16 hi/lo split (hi = RNE(bf16), lo = RNE(v - hi))
// ---------------------------------------------------------------------------
__global__ __launch_bounds__(256) void split_bf16(const float* __restrict__ src,
                                                  unsigned short* __restrict__ hi,
                                                  unsigned short* __restrict__ lo,
                                                  int n4) {
    const int stride = gridDim.x * blockDim.x;
    for (int i = blockIdx.x * blockDim.x + threadIdx.x; i < n4; i += stride) {
        const float4 v = ((const float4*)src)[i];
        ushort4 h, l;
        h.x = f2bf(v.x); l.x = f2bf(v.x - bf2f(h.x));
        h.y = f2bf(v.y); l.y = f2bf(v.y - bf2f(h.y));
        h.z = f2bf(v.z); l.z = f2bf(v.z - bf2f(h.z));
        h.w = f2bf(v.w); l.w = f2bf(v.w - bf2f(h.w));
        ((ushort4*)hi)[i] = h;
        ((ushort4*)lo)[i] = l;
    }
}

// ---------------------------------------------------------------------------
// Stage one 128x32 bf16 tile (linear [128][32]) via global_load_lds.
// Wave w covers chunks 2w, 2w+1 (1024B each). K stride of source = 1024 elems.
// ---------------------------------------------------------------------------
__device__ __forceinline__ void stage_tile(const unsigned short* __restrict__ src,
                                           int row0, int kt,
                                           unsigned short* lds, int wave, int lane) {
#pragma unroll
    for (int i = 0; i < 2; ++i) {
        const int c = wave * 2 + i;
        const int r = c * 16 + (lane >> 2);
        const int kq = (lane & 3) * 8;
        GLOAD_LDS16(src + (size_t)(row0 + r) * 1024 + kt + kq, lds + c * 512);
    }
}

// ---------------------------------------------------------------------------
// Kernel 1: kqv = x @ W^T + b (bf16x3 product split, fp32 acc), write bf16
// K/Q/V in [B,H,S,D]. 128x128 tile, 4 waves (2x2), 4x4 16x16 frags per wave.
// ---------------------------------------------------------------------------
__global__ __launch_bounds__(256) void gemm_qkv_mfma(
    const unsigned short* __restrict__ xh, const unsigned short* __restrict__ xl,
    const unsigned short* __restrict__ wh, const unsigned short* __restrict__ wl,
    const float* __restrict__ bias,
    unsigned short* __restrict__ Ko, unsigned short* __restrict__ Qo,
    unsigned short* __restrict__ Vo) {
    __shared__ unsigned short Ah[128 * 32], Al[128 * 32];
    __shared__ unsigned short Bh[128 * 32], Bl[128 * 32];

    const int t = threadIdx.x, lane = t & 63, w = t >> 6;
    const int wr = w >> 1, wc = w & 1;
    const int g8 = (lane >> 4) * 8, g4 = (lane >> 4) * 4, l15 = lane & 15;
    const int m0 = blockIdx.x * 128, n0 = blockIdx.y * 128;

    f32x4 acc[4][4] = {};

    for (int kt = 0; kt < 1024; kt += 32) {
        stage_tile(xh, m0, kt, Ah, w, lane);
        stage_tile(xl, m0, kt, Al, w, lane);
        stage_tile(wh, n0, kt, Bh, w, lane);
        stage_tile(wl, n0, kt, Bl, w, lane);
        __syncthreads();   // drains vmcnt -> staged tiles visible

        bf16x8 ah[4], al[4], bh[4], bl[4];
#pragma unroll
        for (int m = 0; m < 4; ++m) {
            const int r = (wr * 64 + m * 16 + l15) * 32 + g8;
            ah[m] = *(const bf16x8*)&Ah[r];
            al[m] = *(const bf16x8*)&Al[r];
        }
#pragma unroll
        for (int n = 0; n < 4; ++n) {
            const int r = (wc * 64 + n * 16 + l15) * 32 + g8;
            bh[n] = *(const bf16x8*)&Bh[r];
            bl[n] = *(const bf16x8*)&Bl[r];
        }
#pragma unroll
        for (int m = 0; m < 4; ++m)
#pragma unroll
            for (int n = 0; n < 4; ++n) {
                acc[m][n] = __builtin_amdgcn_mfma_f32_16x16x32_bf16(ah[m], bh[n], acc[m][n], 0, 0, 0);
                acc[m][n] = __builtin_amdgcn_mfma_f32_16x16x32_bf16(ah[m], bl[n], acc[m][n], 0, 0, 0);
                acc[m][n] = __builtin_amdgcn_mfma_f32_16x16x32_bf16(al[m], bh[n], acc[m][n], 0, 0, 0);
            }
        __syncthreads();   // frag reads done before next-tile overwrite
    }

    // epilogue: +bias, cast bf16, scatter to K/Q/V [B,H,S,D] (split order k,q,v)
#pragma unroll
    for (int n = 0; n < 4; ++n) {
        const int col = n0 + wc * 64 + n * 16 + l15;   // [0,3072)
        const float bv = bias[col];
        const int which = col >> 10;
        unsigned short* outp = (which == 0) ? Ko : (which == 1 ? Qo : Vo);
        const int cm = col & 1023, h = cm >> 6, d = cm & 63;
#pragma unroll
        for (int m = 0; m < 4; ++m)
#pragma unroll
            for (int jj = 0; jj < 4; ++jj) {
                const int row = m0 + wr * 64 + m * 16 + g4 + jj;
                const int b = row >> 11, s = row & 2047;
                outp[(((size_t)(b * NH + h) * SEQ + s) << 6) + d] =
                    f2bf(acc[m][n][jj] + bv);
            }
    }
}

// ---------------------------------------------------------------------------
// Kernel 3: out = Y @ W_proj^T + b (Y already bf16; W in hi/lo -> 2-term)
// ---------------------------------------------------------------------------
__global__ __launch_bounds__(256) void gemm_proj_mfma(
    const unsigned short* __restrict__ Yb,
    const unsigned short* __restrict__ wh, const unsigned short* __restrict__ wl,
    const float* __restrict__ bias, float* __restrict__ Out) {
    __shared__ unsigned short Ah[128 * 32];
    __shared__ unsigned short Bh[128 * 32], Bl[128 * 32];

    const int t = threadIdx.x, lane = t & 63, w = t >> 6;
    const int wr = w >> 1, wc = w & 1;
    const int g8 = (lane >> 4) * 8, g4 = (lane >> 4) * 4, l15 = lane & 15;
    const int m0 = blockIdx.x * 128, n0 = blockIdx.y * 128;

    f32x4 acc[4][4] = {};

    for (int kt = 0; kt < 1024; kt += 32) {
        stage_tile(Yb, m0, kt, Ah, w, lane);
        stage_tile(wh, n0, kt, Bh, w, lane);
        stage_tile(wl, n0, kt, Bl, w, lane);
        __syncthreads();

        bf16x8 a[4], bh[4], bl[4];
#pragma unroll
        for (int m = 0; m < 4; ++m)
            a[m] = *(const bf16x8*)&Ah[(wr * 64 + m * 16 + l15) * 32 + g8];
#pragma unroll
        for (int n = 0; n < 4; ++n) {
            const int r = (wc * 64 + n * 16 + l15) * 32 + g8;
            bh[n] = *(const bf16x8*)&Bh[r];
            bl[n] = *(const bf16x8*)&Bl[r];
        }
#pragma unroll
        for (int m = 0; m < 4; ++m)
#pragma unroll
            for (int n = 0; n < 4; ++n) {
                acc[m][n] = __builtin_amdgcn_mfma_f32_16x16x32_bf16(a[m], bh[n], acc[m][n], 0, 0, 0);
                acc[m][n] = __builtin_amdgcn_mfma_f32_16x16x32_bf16(a[m], bl[n], acc[m][n], 0, 0, 0);
            }
        __syncthreads();
    }

#pragma unroll
    for (int n = 0; n < 4; ++n) {
        const int col = n0 + wc * 64 + n * 16 + l15;
        const float bv = bias[col];
#pragma unroll
        for (int m = 0; m < 4; ++m)
#pragma unroll
            for (int jj = 0; jj < 4; ++jj) {
                const int row = m0 + wr * 64 + m * 16 + g4 + jj;
                Out[(size_t)row * EMB + col] = acc[m][n][jj] + bv;
            }
    }
}

// ---------------------------------------------------------------------------
// Kernel 2: causal flash attention, bf16 MFMA.
// Grid (S/64, B*H), 256 thr = 4 waves; wave w owns q-rows w*16..w*16+15.
// K row-major [64][72] LDS (padded), V transposed [d][kv] [64][72], P per-wave.
// ---------------------------------------------------------------------------
__global__ __launch_bounds__(256) void attn_mfma(
    const unsigned short* __restrict__ Kt, const unsigned short* __restrict__ Qt,
    const unsigned short* __restrict__ Vg, unsigned short* __restrict__ Y) {
    __shared__ unsigned short Ks[64][72];
    __shared__ unsigned short Vs[64][72];   // Vs[d][kv]
    __shared__ unsigned short Ps[64][72];   // rows w*16.. per wave (private)

    const int qt = blockIdx.x, bh = blockIdx.y;
    const int b = bh >> 4, h = bh & 15;
    const unsigned short* Qp = Qt + ((size_t)bh * SEQ << 6);
    const unsigned short* Kp = Kt + ((size_t)bh * SEQ << 6);
    const unsigned short* Vp = Vg + ((size_t)bh * SEQ << 6);

    const int t = threadIdx.x, lane = t & 63, w = t >> 6;
    const int g8 = (lane >> 4) * 8, g4 = (lane >> 4) * 4, l15 = lane & 15;
    const int qbase = qt * 64 + w * 16;

    // Q fragments held in registers for the whole kernel
    bf16x8 qf[2];
#pragma unroll
    for (int kc = 0; kc < 2; ++kc)
        qf[kc] = *(const bf16x8*)(Qp + ((size_t)(qbase + l15) << 6) + kc * 32 + g8);

    float m_i[4], l_i[4];
    f32x4 o_acc[4] = {};
#pragma unroll
    for (int jj = 0; jj < 4; ++jj) { m_i[jj] = -1e30f; l_i[jj] = 0.f; }

    union U8 { uint4 q; unsigned short u[8]; };
    U8 kreg[2], vreg[2];
    auto loadKV = [&](int tile) {
#pragma unroll
        for (int i = 0; i < 2; ++i) {
            const int c = t + (i << 8);          // 0..511
            const int r = c >> 3, col = (c & 7) * 8;
            kreg[i].q = *(const uint4*)(Kp + ((size_t)tile << 12) + r * 64 + col);
            vreg[i].q = *(const uint4*)(Vp + ((size_t)tile << 12) + r * 64 + col);
        }
    };

    loadKV(0);
    const int ntiles = qt + 1;
    for (int tile = 0; tile < ntiles; ++tile) {
        __syncthreads();   // prev tile's LDS reads done
#pragma unroll
        for (int i = 0; i < 2; ++i) {
            const int c = t + (i << 8);
            const int r = c >> 3, col = (c & 7) * 8;
            *(uint4*)&Ks[r][col] = kreg[i].q;
#pragma unroll
            for (int j = 0; j < 8; ++j) Vs[col + j][r] = vreg[i].u[j];
        }
        if (tile + 1 < ntiles) loadKV(tile + 1);   // prefetch next K/V
        __syncthreads();

        // ---- S = Q K^T ----
        f32x4 s[4] = {};
#pragma unroll
        for (int n = 0; n < 4; ++n)
#pragma unroll
            for (int kc = 0; kc < 2; ++kc) {
                bf16x8 kf = *(const bf16x8*)&Ks[n * 16 + l15][kc * 32 + g8];
                s[n] = __builtin_amdgcn_mfma_f32_16x16x32_bf16(qf[kc], kf, s[n], 0, 0, 0);
            }

        // ---- scale + causal mask ----
        const bool diag = (tile == qt);
#pragma unroll
        for (int n = 0; n < 4; ++n)
#pragma unroll
            for (int jj = 0; jj < 4; ++jj) {
                float v = s[n][jj] * 0.125f;
                if (diag) {
                    const int qi = qbase + g4 + jj;
                    const int kj = tile * 64 + n * 16 + l15;
                    if (kj > qi) v = -1e30f;
                }
                s[n][jj] = v;
            }

        // ---- online softmax (rows live in 16-lane groups) ----
        float alpha[4];
#pragma unroll
        for (int jj = 0; jj < 4; ++jj) {
            float rm = fmaxf(fmaxf(s[0][jj], s[1][jj]), fmaxf(s[2][jj], s[3][jj]));
#pragma unroll
            for (int msk = 1; msk < 16; msk <<= 1)
                rm = fmaxf(rm, __shfl_xor(rm, msk, 16));
            const float mnew = fmaxf(m_i[jj], rm);
            alpha[jj] = __expf(m_i[jj] - mnew);
            m_i[jj] = mnew;
        }
        float rsum[4] = {0.f, 0.f, 0.f, 0.f};
#pragma unroll
        for (int n = 0; n < 4; ++n)
#pragma unroll
            for (int jj = 0; jj < 4; ++jj) {
                const float p = __expf(s[n][jj] - m_i[jj]);
                s[n][jj] = p;
                rsum[jj] += p;
            }
#pragma unroll
        for (int jj = 0; jj < 4; ++jj) {
#pragma unroll
            for (int msk = 1; msk < 16; msk <<= 1)
                rsum[jj] += __shfl_xor(rsum[jj], msk, 16);
            l_i[jj] = alpha[jj] * l_i[jj] + rsum[jj];
        }
#pragma unroll
        for (int nd = 0; nd < 4; ++nd)
#pragma unroll
            for (int jj = 0; jj < 4; ++jj) o_acc[nd][jj] *= alpha[jj];

        // ---- P -> LDS (C-layout -> A-layout relayout; wave-private rows) ----
#pragma unroll
        for (int n = 0; n < 4; ++n)
#pragma unroll
            for (int jj = 0; jj < 4; ++jj)
                Ps[w * 16 + g4 + jj][n * 16 + l15] = f2bf(s[n][jj]);

        // ---- O += P V ---- (same-wave DS dependency; compiler inserts lgkmcnt)
#pragma unroll
        for (int kc = 0; kc < 2; ++kc) {
            bf16x8 pf = *(const bf16x8*)&Ps[w * 16 + l15][kc * 32 + g8];
#pragma unroll
            for (int nd = 0; nd < 4; ++nd) {
                bf16x8 vf = *(const bf16x8*)&Vs[nd * 16 + l15][kc * 32 + g8];
                o_acc[nd] = __builtin_amdgcn_mfma_f32_16x16x32_bf16(pf, vf, o_acc[nd], 0, 0, 0);
            }
        }
    }

    // epilogue: O/l -> bf16 -> Y[B,S,E]
#pragma unroll
    for (int jj = 0; jj < 4; ++jj) {
        const float inv = 1.0f / l_i[jj];
        const int srow = qbase + g4 + jj;
#pragma unroll
        for (int nd = 0; nd < 4; ++nd)
            Y[((size_t)(b * SEQ + srow) << 10) + (h << 6) + nd * 16 + l15] =
                f2bf(o_acc[nd][jj] * inv);
    }
}

// ---------------------------------------------------------------------------
extern "C" void kernel_launch(void* const* d_in, const int* in_sizes, int n_in,
                              void* d_out, int out_size, void* d_ws, size_t ws_size,
                              hipStream_t stream) {
    const float* x  = (const float*)d_in[0];
    const float* Wk = (const float*)d_in[1];
    const float* bk = (const float*)d_in[2];
    const float* Wp = (const float*)d_in[3];
    const float* bp = (const float*)d_in[4];
    float* out = (float*)d_out;

    char* ws = (char*)d_ws;
    const size_t MB = 1024 * 1024;
    unsigned short* xh  = (unsigned short*)(ws + 0 * MB);
    unsigned short* xl  = (unsigned short*)(ws + 16 * MB);
    unsigned short* wkh = (unsigned short*)(ws + 32 * MB);
    unsigned short* wkl = (unsigned short*)(ws + 38 * MB);
    unsigned short* wph = (unsigned short*)(ws + 44 * MB);
    unsigned short* wpl = (unsigned short*)(ws + 46 * MB);
    unsigned short* Ko  = (unsigned short*)(ws + 48 * MB);
    unsigned short* Qo  = (unsigned short*)(ws + 64 * MB);
    unsigned short* Vo  = (unsigned short*)(ws + 80 * MB);
    unsigned short* Yo  = (unsigned short*)(ws + 96 * MB);   // 112 MiB total

    split_bf16<<<512, 256, 0, stream>>>(x,  xh,  xl,  (BATCH * SEQ * EMB) / 4);
    split_bf16<<<256, 256, 0, stream>>>(Wk, wkh, wkl, (3 * EMB * EMB) / 4);
    split_bf16<<<128, 256, 0, stream>>>(Wp, wph, wpl, (EMB * EMB) / 4);

    gemm_qkv_mfma<<<dim3(MROWS / 128, 3072 / 128), 256, 0, stream>>>(
        xh, xl, wkh, wkl, bk, Ko, Qo, Vo);
    attn_mfma<<<dim3(SEQ / 64, BATCH * NH), 256, 0, stream>>>(Ko, Qo, Vo, Yo);
    gemm_proj_mfma<<<dim3(MROWS / 128, EMB / 128), 256, 0, stream>>>(
        Yo, wph, wpl, bp, out);
}

// Round 3
// 631.194 us; speedup vs baseline: 3.8883x; 1.0047x over previous
//
#include <hip/hip_runtime.h>
#include <cstddef>
#include <cstdint>

#define EMB 1024
#define NH 16
#define HD 64
#define BATCH 4
#define SEQ 2048
#define MROWS (BATCH * SEQ)   // 8192

typedef __attribute__((ext_vector_type(8))) short bf16x8;   // 8 bf16 in 4 VGPRs
typedef __attribute__((ext_vector_type(4))) float f32x4;    // MFMA C/D

__device__ __forceinline__ float bf2f(unsigned short u) {
    union { unsigned int i; float f; } c; c.i = ((unsigned int)u) << 16; return c.f;
}
__device__ __forceinline__ unsigned short f2bf(float f) {   // RNE
    union { float f; unsigned int i; } c; c.f = f;
    return (unsigned short)((c.i + 0x7FFFu + ((c.i >> 16) & 1u)) >> 16);
}

// async global->LDS, 16B per lane. LDS dest must be wave-uniform base; HW adds lane*16.
#define GLOAD_LDS16(gp, lp) __builtin_amdgcn_global_load_lds(                  \
    (const __attribute__((address_space(1))) void*)(gp),                       \
    (__attribute__((address_space(3))) void*)(lp), 16, 0, 0)

// ---------------------------------------------------------------------------
// fp32 -> bf16 hi/lo split (hi = RNE(bf16), lo = RNE(v - hi))
// ---------------------------------------------------------------------------
__global__ __launch_bounds__(256) void split_bf16(const float* __restrict__ src,
                                                  unsigned short* __restrict__ hi,
                                                  unsigned short* __restrict__ lo,
                                                  int n4) {
    const int stride = gridDim.x * blockDim.x;
    for (int i = blockIdx.x * blockDim.x + threadIdx.x; i < n4; i += stride) {
        const float4 v = ((const float4*)src)[i];
        ushort4 h, l;
        h.x = f2bf(v.x); l.x = f2bf(v.x - bf2f(h.x));
        h.y = f2bf(v.y); l.y = f2bf(v.y - bf2f(h.y));
        h.z = f2bf(v.z); l.z = f2bf(v.z - bf2f(h.z));
        h.w = f2bf(v.w); l.w = f2bf(v.w - bf2f(h.w));
        ((ushort4*)hi)[i] = h;
        ((ushort4*)lo)[i] = l;
    }
}

// ---------------------------------------------------------------------------
// Stage one 128x32 bf16 tile (linear [128][32]) via global_load_lds.
// ---------------------------------------------------------------------------
__device__ __forceinline__ void stage_tile(const unsigned short* __restrict__ src,
                                           int row0, int kt,
                                           unsigned short* lds, int wave, int lane) {
#pragma unroll
    for (int i = 0; i < 2; ++i) {
        const int c = wave * 2 + i;
        const int r = c * 16 + (lane >> 2);
        const int kq = (lane & 3) * 8;
        GLOAD_LDS16(src + (size_t)(row0 + r) * 1024 + kt + kq, lds + c * 512);
    }
}

// ---------------------------------------------------------------------------
// Kernel 1: kqv = x @ W^T + b (bf16x3 product split, fp32 acc), write bf16
// K/Q/V in [B,H,S,D]. 128x128 tile, 4 waves (2x2), 4x4 16x16 frags per wave.
// ---------------------------------------------------------------------------
__global__ __launch_bounds__(256) void gemm_qkv_mfma(
    const unsigned short* __restrict__ xh, const unsigned short* __restrict__ xl,
    const unsigned short* __restrict__ wh, const unsigned short* __restrict__ wl,
    const float* __restrict__ bias,
    unsigned short* __restrict__ Ko, unsigned short* __restrict__ Qo,
    unsigned short* __restrict__ Vo) {
    __shared__ unsigned short Ah[128 * 32], Al[128 * 32];
    __shared__ unsigned short Bh[128 * 32], Bl[128 * 32];

    const int t = threadIdx.x, lane = t & 63, w = t >> 6;
    const int wr = w >> 1, wc = w & 1;
    const int g8 = (lane >> 4) * 8, g4 = (lane >> 4) * 4, l15 = lane & 15;

    // XCD-aware swizzle: contiguous n-tile chunks per XCD (B-panel L2 reuse)
    const int nwg = 64 * 24;                       // 1536, %8 == 0
    const int lin = blockIdx.x + gridDim.x * blockIdx.y;
    const int swz = (lin & 7) * (nwg >> 3) + (lin >> 3);
    const int m0 = (swz & 63) * 128, n0 = (swz >> 6) * 128;

    f32x4 acc[4][4] = {};

    for (int kt = 0; kt < 1024; kt += 32) {
        stage_tile(xh, m0, kt, Ah, w, lane);
        stage_tile(xl, m0, kt, Al, w, lane);
        stage_tile(wh, n0, kt, Bh, w, lane);
        stage_tile(wl, n0, kt, Bl, w, lane);
        __syncthreads();   // drains vmcnt -> staged tiles visible

        bf16x8 ah[4], al[4], bh[4], bl[4];
#pragma unroll
        for (int m = 0; m < 4; ++m) {
            const int r = (wr * 64 + m * 16 + l15) * 32 + g8;
            ah[m] = *(const bf16x8*)&Ah[r];
            al[m] = *(const bf16x8*)&Al[r];
        }
#pragma unroll
        for (int n = 0; n < 4; ++n) {
            const int r = (wc * 64 + n * 16 + l15) * 32 + g8;
            bh[n] = *(const bf16x8*)&Bh[r];
            bl[n] = *(const bf16x8*)&Bl[r];
        }
#pragma unroll
        for (int m = 0; m < 4; ++m)
#pragma unroll
            for (int n = 0; n < 4; ++n) {
                acc[m][n] = __builtin_amdgcn_mfma_f32_16x16x32_bf16(ah[m], bh[n], acc[m][n], 0, 0, 0);
                acc[m][n] = __builtin_amdgcn_mfma_f32_16x16x32_bf16(ah[m], bl[n], acc[m][n], 0, 0, 0);
                acc[m][n] = __builtin_amdgcn_mfma_f32_16x16x32_bf16(al[m], bh[n], acc[m][n], 0, 0, 0);
            }
        __syncthreads();   // frag reads done before next-tile overwrite
    }

    // epilogue: +bias, cast bf16, scatter to K/Q/V [B,H,S,D] (split order k,q,v)
#pragma unroll
    for (int n = 0; n < 4; ++n) {
        const int col = n0 + wc * 64 + n * 16 + l15;   // [0,3072)
        const float bv = bias[col];
        const int which = col >> 10;
        unsigned short* outp = (which == 0) ? Ko : (which == 1 ? Qo : Vo);
        const int cm = col & 1023, h = cm >> 6, d = cm & 63;
#pragma unroll
        for (int m = 0; m < 4; ++m)
#pragma unroll
            for (int jj = 0; jj < 4; ++jj) {
                const int row = m0 + wr * 64 + m * 16 + g4 + jj;
                const int b = row >> 11, s = row & 2047;
                outp[(((size_t)(b * NH + h) * SEQ + s) << 6) + d] =
                    f2bf(acc[m][n][jj] + bv);
            }
    }
}

// ---------------------------------------------------------------------------
// Kernel 3: out = Y @ W_proj^T + b (Y already bf16; W in hi/lo -> 2-term)
// ---------------------------------------------------------------------------
__global__ __launch_bounds__(256) void gemm_proj_mfma(
    const unsigned short* __restrict__ Yb,
    const unsigned short* __restrict__ wh, const unsigned short* __restrict__ wl,
    const float* __restrict__ bias, float* __restrict__ Out) {
    __shared__ unsigned short Ah[128 * 32];
    __shared__ unsigned short Bh[128 * 32], Bl[128 * 32];

    const int t = threadIdx.x, lane = t & 63, w = t >> 6;
    const int wr = w >> 1, wc = w & 1;
    const int g8 = (lane >> 4) * 8, g4 = (lane >> 4) * 4, l15 = lane & 15;

    const int nwg = 64 * 8;                        // 512
    const int lin = blockIdx.x + gridDim.x * blockIdx.y;
    const int swz = (lin & 7) * (nwg >> 3) + (lin >> 3);
    const int m0 = (swz & 63) * 128, n0 = (swz >> 6) * 128;

    f32x4 acc[4][4] = {};

    for (int kt = 0; kt < 1024; kt += 32) {
        stage_tile(Yb, m0, kt, Ah, w, lane);
        stage_tile(wh, n0, kt, Bh, w, lane);
        stage_tile(wl, n0, kt, Bl, w, lane);
        __syncthreads();

        bf16x8 a[4], bh[4], bl[4];
#pragma unroll
        for (int m = 0; m < 4; ++m)
            a[m] = *(const bf16x8*)&Ah[(wr * 64 + m * 16 + l15) * 32 + g8];
#pragma unroll
        for (int n = 0; n < 4; ++n) {
            const int r = (wc * 64 + n * 16 + l15) * 32 + g8;
            bh[n] = *(const bf16x8*)&Bh[r];
            bl[n] = *(const bf16x8*)&Bl[r];
        }
#pragma unroll
        for (int m = 0; m < 4; ++m)
#pragma unroll
            for (int n = 0; n < 4; ++n) {
                acc[m][n] = __builtin_amdgcn_mfma_f32_16x16x32_bf16(a[m], bh[n], acc[m][n], 0, 0, 0);
                acc[m][n] = __builtin_amdgcn_mfma_f32_16x16x32_bf16(a[m], bl[n], acc[m][n], 0, 0, 0);
            }
        __syncthreads();
    }

#pragma unroll
    for (int n = 0; n < 4; ++n) {
        const int col = n0 + wc * 64 + n * 16 + l15;
        const float bv = bias[col];
#pragma unroll
        for (int m = 0; m < 4; ++m)
#pragma unroll
            for (int jj = 0; jj < 4; ++jj) {
                const int row = m0 + wr * 64 + m * 16 + g4 + jj;
                Out[(size_t)row * EMB + col] = acc[m][n][jj] + bv;
            }
    }
}

// ---------------------------------------------------------------------------
// Kernel 2: causal flash attention, bf16 MFMA.
// 1D grid 1024 (XCD-swizzled -> qt in [0,16), bh in [0,64)), 256 thr = 4 waves.
// Wave w owns 32 q-rows: {qt*128 + rb*64 + w*16 + 0..15} for rb = 0,1.
// Pads chosen for conflict-free access: Ks 72, Vs 65, Ps 68.
// ---------------------------------------------------------------------------
__global__ __launch_bounds__(256) void attn_mfma(
    const unsigned short* __restrict__ Kt, const unsigned short* __restrict__ Qt,
    const unsigned short* __restrict__ Vg, unsigned short* __restrict__ Y) {
    __shared__ unsigned short Ks[64][72];
    __shared__ unsigned short Vs[64][65];   // Vs[d][kv], pad 65: transpose-write ~2-way
    __shared__ unsigned short Ps[128][68];  // pad 68: scatter-write conflict-free

    // XCD swizzle: all 16 q-tiles of 8 consecutive bh per XCD (K/V L2-resident)
    const int lin = blockIdx.x;             // 0..1023
    const int swz = (lin & 7) * 128 + (lin >> 3);
    const int qt = swz & 15, bh = swz >> 4;
    const int b = bh >> 4, h = bh & 15;
    const unsigned short* Qp = Qt + ((size_t)bh * SEQ << 6);
    const unsigned short* Kp = Kt + ((size_t)bh * SEQ << 6);
    const unsigned short* Vp = Vg + ((size_t)bh * SEQ << 6);

    const int t = threadIdx.x, lane = t & 63, w = t >> 6;
    const int g8 = (lane >> 4) * 8, g4 = (lane >> 4) * 4, l15 = lane & 15;

    // Q fragments (2 row-blocks x 2 k-chunks) held in registers throughout
    bf16x8 qf[2][2];
#pragma unroll
    for (int rb = 0; rb < 2; ++rb)
#pragma unroll
        for (int kc = 0; kc < 2; ++kc)
            qf[rb][kc] = *(const bf16x8*)(
                Qp + ((size_t)(qt * 128 + rb * 64 + w * 16 + l15) << 6) + kc * 32 + g8);

    float m_i[2][4], l_i[2][4];
    f32x4 o_acc[2][4] = {};
#pragma unroll
    for (int rb = 0; rb < 2; ++rb)
#pragma unroll
        for (int jj = 0; jj < 4; ++jj) { m_i[rb][jj] = -1e30f; l_i[rb][jj] = 0.f; }

    union U8 { uint4 q; unsigned short u[8]; };
    U8 kreg[2], vreg[2];
    auto loadKV = [&](int tile) {
#pragma unroll
        for (int i = 0; i < 2; ++i) {
            const int c = t + (i << 8);          // 0..511
            const int r = c >> 3, col = (c & 7) * 8;
            kreg[i].q = *(const uint4*)(Kp + ((size_t)tile << 12) + r * 64 + col);
            vreg[i].q = *(const uint4*)(Vp + ((size_t)tile << 12) + r * 64 + col);
        }
    };

    const float SCL = 0.125f * 1.44269504f;   // scale * log2(e); exp -> exp2

    loadKV(0);
    const int ntiles = 2 * qt + 2;
    for (int tile = 0; tile < ntiles; ++tile) {
        __syncthreads();   // prev tile's LDS reads done
#pragma unroll
        for (int i = 0; i < 2; ++i) {
            const int c = t + (i << 8);
            const int r = c >> 3, col = (c & 7) * 8;
            *(uint4*)&Ks[r][col] = kreg[i].q;
#pragma unroll
            for (int j = 0; j < 8; ++j) Vs[col + j][r] = vreg[i].u[j];
        }
        if (tile + 1 < ntiles) loadKV(tile + 1);   // prefetch next K/V
        __syncthreads();

        // K fragments shared across both row-blocks
        bf16x8 kf[4][2];
#pragma unroll
        for (int n = 0; n < 4; ++n)
#pragma unroll
            for (int kc = 0; kc < 2; ++kc)
                kf[n][kc] = *(const bf16x8*)&Ks[n * 16 + l15][kc * 32 + g8];

#pragma unroll
        for (int rb = 0; rb < 2; ++rb) {
            const int q0 = qt * 128 + rb * 64 + w * 16;
            if (tile * 64 > q0 + 15) continue;        // fully-masked (wave-uniform)

            f32x4 s[4] = {};
#pragma unroll
            for (int n = 0; n < 4; ++n)
#pragma unroll
                for (int kc = 0; kc < 2; ++kc)
                    s[n] = __builtin_amdgcn_mfma_f32_16x16x32_bf16(qf[rb][kc], kf[n][kc], s[n], 0, 0, 0);

            const bool domask = (tile * 64 + 63 > q0);
#pragma unroll
            for (int n = 0; n < 4; ++n)
#pragma unroll
                for (int jj = 0; jj < 4; ++jj) {
                    float v = s[n][jj] * SCL;
                    if (domask) {
                        const int qi = q0 + g4 + jj;
                        const int kj = tile * 64 + n * 16 + l15;
                        if (kj > qi) v = -1e30f;
                    }
                    s[n][jj] = v;
                }

            // online softmax (rows live in 16-lane groups), log2 domain
            float alpha[4];
#pragma unroll
            for (int jj = 0; jj < 4; ++jj) {
                float rm = fmaxf(fmaxf(s[0][jj], s[1][jj]), fmaxf(s[2][jj], s[3][jj]));
#pragma unroll
                for (int msk = 1; msk < 16; msk <<= 1)
                    rm = fmaxf(rm, __shfl_xor(rm, msk, 16));
                const float mnew = fmaxf(m_i[rb][jj], rm);
                alpha[jj] = exp2f(m_i[rb][jj] - mnew);
                m_i[rb][jj] = mnew;
            }
            float rsum[4] = {0.f, 0.f, 0.f, 0.f};
#pragma unroll
            for (int n = 0; n < 4; ++n)
#pragma unroll
                for (int jj = 0; jj < 4; ++jj) {
                    const float p = exp2f(s[n][jj] - m_i[rb][jj]);
                    s[n][jj] = p;
                    rsum[jj] += p;
                }
#pragma unroll
            for (int jj = 0; jj < 4; ++jj) {
#pragma unroll
                for (int msk = 1; msk < 16; msk <<= 1)
                    rsum[jj] += __shfl_xor(rsum[jj], msk, 16);
                l_i[rb][jj] = alpha[jj] * l_i[rb][jj] + rsum[jj];
            }
#pragma unroll
            for (int nd = 0; nd < 4; ++nd)
#pragma unroll
                for (int jj = 0; jj < 4; ++jj) o_acc[rb][nd][jj] *= alpha[jj];

            // P -> LDS (C-layout -> A-layout relayout; wave-private rows)
#pragma unroll
            for (int n = 0; n < 4; ++n)
#pragma unroll
                for (int jj = 0; jj < 4; ++jj)
                    Ps[w * 32 + rb * 16 + g4 + jj][n * 16 + l15] = f2bf(s[n][jj]);
        }

        // ---- O += P V ---- (V frags shared across row-blocks)
#pragma unroll
        for (int kc = 0; kc < 2; ++kc) {
            bf16x8 vf[4];
#pragma unroll
            for (int nd = 0; nd < 4; ++nd)
                vf[nd] = *(const bf16x8*)&Vs[nd * 16 + l15][kc * 32 + g8];
#pragma unroll
            for (int rb = 0; rb < 2; ++rb) {
                const int q0 = qt * 128 + rb * 64 + w * 16;
                if (tile * 64 > q0 + 15) continue;
                bf16x8 pf = *(const bf16x8*)&Ps[w * 32 + rb * 16 + l15][kc * 32 + g8];
#pragma unroll
                for (int nd = 0; nd < 4; ++nd)
                    o_acc[rb][nd] = __builtin_amdgcn_mfma_f32_16x16x32_bf16(pf, vf[nd], o_acc[rb][nd], 0, 0, 0);
            }
        }
    }

    // epilogue: O/l -> bf16 -> Y[B,S,E]
#pragma unroll
    for (int rb = 0; rb < 2; ++rb)
#pragma unroll
        for (int jj = 0; jj < 4; ++jj) {
            const float inv = 1.0f / l_i[rb][jj];
            const int srow = qt * 128 + rb * 64 + w * 16 + g4 + jj;
#pragma unroll
            for (int nd = 0; nd < 4; ++nd)
                Y[((size_t)(b * SEQ + srow) << 10) + (h << 6) + nd * 16 + l15] =
                    f2bf(o_acc[rb][nd][jj] * inv);
        }
}

// ---------------------------------------------------------------------------
extern "C" void kernel_launch(void* const* d_in, const int* in_sizes, int n_in,
                              void* d_out, int out_size, void* d_ws, size_t ws_size,
                              hipStream_t stream) {
    const float* x  = (const float*)d_in[0];
    const float* Wk = (const float*)d_in[1];
    const float* bk = (const float*)d_in[2];
    const float* Wp = (const float*)d_in[3];
    const float* bp = (const float*)d_in[4];
    float* out = (float*)d_out;

    char* ws = (char*)d_ws;
    const size_t MB = 1024 * 1024;
    unsigned short* xh  = (unsigned short*)(ws + 0 * MB);
    unsigned short* xl  = (unsigned short*)(ws + 16 * MB);
    unsigned short* wkh = (unsigned short*)(ws + 32 * MB);
    unsigned short* wkl = (unsigned short*)(ws + 38 * MB);
    unsigned short* wph = (unsigned short*)(ws + 44 * MB);
    unsigned short* wpl = (unsigned short*)(ws + 46 * MB);
    unsigned short* Ko  = (unsigned short*)(ws + 48 * MB);
    unsigned short* Qo  = (unsigned short*)(ws + 64 * MB);
    unsigned short* Vo  = (unsigned short*)(ws + 80 * MB);
    unsigned short* Yo  = (unsigned short*)(ws + 96 * MB);   // 112 MiB total

    split_bf16<<<512, 256, 0, stream>>>(x,  xh,  xl,  (BATCH * SEQ * EMB) / 4);
    split_bf16<<<256, 256, 0, stream>>>(Wk, wkh, wkl, (3 * EMB * EMB) / 4);
    split_bf16<<<128, 256, 0, stream>>>(Wp, wph, wpl, (EMB * EMB) / 4);

    gemm_qkv_mfma<<<dim3(MROWS / 128, 3072 / 128), 256, 0, stream>>>(
        xh, xl, wkh, wkl, bk, Ko, Qo, Vo);
    attn_mfma<<<1024, 256, 0, stream>>>(Ko, Qo, Vo, Yo);
    gemm_proj_mfma<<<dim3(MROWS / 128, EMB / 128), 256, 0, stream>>>(
        Yo, wph, wpl, bp, out);
}

// Round 5
// 458.497 us; speedup vs baseline: 5.3528x; 1.3767x over previous
//
#include <hip/hip_runtime.h>
#include <cstddef>
#include <cstdint>

#define EMB 1024
#define NH 16
#define HD 64
#define BATCH 4
#define SEQ 2048
#define MROWS (BATCH * SEQ)   // 8192

typedef __attribute__((ext_vector_type(8))) short bf16x8;   // 8 bf16 in 4 VGPRs
typedef __attribute__((ext_vector_type(4))) float f32x4;    // MFMA C/D

__device__ __forceinline__ float bf2f(unsigned short u) {
    union { unsigned int i; float f; } c; c.i = ((unsigned int)u) << 16; return c.f;
}
__device__ __forceinline__ unsigned short f2bf(float f) {   // RNE
    union { float f; unsigned int i; } c; c.f = f;
    return (unsigned short)((c.i + 0x7FFFu + ((c.i >> 16) & 1u)) >> 16);
}

// async global->LDS, 16B per lane. LDS dest must be wave-uniform base; HW adds lane*16.
#define GLOAD_LDS16(gp, lp) __builtin_amdgcn_global_load_lds(                  \
    (const __attribute__((address_space(1))) void*)(gp),                       \
    (__attribute__((address_space(3))) void*)(lp), 16, 0, 0)

// ---------------------------------------------------------------------------
// fp32 -> bf16 hi/lo split (hi = RNE(bf16), lo = RNE(v - hi))
// ---------------------------------------------------------------------------
__global__ __launch_bounds__(256) void split_bf16(const float* __restrict__ src,
                                                  unsigned short* __restrict__ hi,
                                                  unsigned short* __restrict__ lo,
                                                  int n4) {
    const int stride = gridDim.x * blockDim.x;
    for (int i = blockIdx.x * blockDim.x + threadIdx.x; i < n4; i += stride) {
        const float4 v = ((const float4*)src)[i];
        ushort4 h, l;
        h.x = f2bf(v.x); l.x = f2bf(v.x - bf2f(h.x));
        h.y = f2bf(v.y); l.y = f2bf(v.y - bf2f(h.y));
        h.z = f2bf(v.z); l.z = f2bf(v.z - bf2f(h.z));
        h.w = f2bf(v.w); l.w = f2bf(v.w - bf2f(h.w));
        ((ushort4*)hi)[i] = h;
        ((ushort4*)lo)[i] = l;
    }
}

// ---------------------------------------------------------------------------
// Stage one 128x32 bf16 tile (linear [128][32]) via global_load_lds.
// ---------------------------------------------------------------------------
__device__ __forceinline__ void stage_tile(const unsigned short* __restrict__ src,
                                           int row0, int kt,
                                           unsigned short* lds, int wave, int lane) {
#pragma unroll
    for (int i = 0; i < 2; ++i) {
        const int c = wave * 2 + i;
        const int r = c * 16 + (lane >> 2);
        const int kq = (lane & 3) * 8;
        GLOAD_LDS16(src + (size_t)(row0 + r) * 1024 + kt + kq, lds + c * 512);
    }
}

// ---------------------------------------------------------------------------
// Kernel 1: kqv = x @ W^T + b (bf16x3 product split, fp32 acc), write bf16
// K/Q/V in [B,H,S,D]. 128x128 tile, 4 waves (2x2), 4x4 16x16 frags per wave.
// ---------------------------------------------------------------------------
__global__ __launch_bounds__(256) void gemm_qkv_mfma(
    const unsigned short* __restrict__ xh, const unsigned short* __restrict__ xl,
    const unsigned short* __restrict__ wh, const unsigned short* __restrict__ wl,
    const float* __restrict__ bias,
    unsigned short* __restrict__ Ko, unsigned short* __restrict__ Qo,
    unsigned short* __restrict__ Vo) {
    __shared__ unsigned short Ah[128 * 32], Al[128 * 32];
    __shared__ unsigned short Bh[128 * 32], Bl[128 * 32];

    const int t = threadIdx.x, lane = t & 63, w = t >> 6;
    const int wr = w >> 1, wc = w & 1;
    const int g8 = (lane >> 4) * 8, g4 = (lane >> 4) * 4, l15 = lane & 15;

    const int nwg = 64 * 24;                       // 1536, %8 == 0
    const int lin = blockIdx.x + gridDim.x * blockIdx.y;
    const int swz = (lin & 7) * (nwg >> 3) + (lin >> 3);
    const int m0 = (swz & 63) * 128, n0 = (swz >> 6) * 128;

    f32x4 acc[4][4] = {};

    for (int kt = 0; kt < 1024; kt += 32) {
        stage_tile(xh, m0, kt, Ah, w, lane);
        stage_tile(xl, m0, kt, Al, w, lane);
        stage_tile(wh, n0, kt, Bh, w, lane);
        stage_tile(wl, n0, kt, Bl, w, lane);
        __syncthreads();   // drains vmcnt -> staged tiles visible

        bf16x8 ah[4], al[4], bh[4], bl[4];
#pragma unroll
        for (int m = 0; m < 4; ++m) {
            const int r = (wr * 64 + m * 16 + l15) * 32 + g8;
            ah[m] = *(const bf16x8*)&Ah[r];
            al[m] = *(const bf16x8*)&Al[r];
        }
#pragma unroll
        for (int n = 0; n < 4; ++n) {
            const int r = (wc * 64 + n * 16 + l15) * 32 + g8;
            bh[n] = *(const bf16x8*)&Bh[r];
            bl[n] = *(const bf16x8*)&Bl[r];
        }
#pragma unroll
        for (int m = 0; m < 4; ++m)
#pragma unroll
            for (int n = 0; n < 4; ++n) {
                acc[m][n] = __builtin_amdgcn_mfma_f32_16x16x32_bf16(ah[m], bh[n], acc[m][n], 0, 0, 0);
                acc[m][n] = __builtin_amdgcn_mfma_f32_16x16x32_bf16(ah[m], bl[n], acc[m][n], 0, 0, 0);
                acc[m][n] = __builtin_amdgcn_mfma_f32_16x16x32_bf16(al[m], bh[n], acc[m][n], 0, 0, 0);
            }
        __syncthreads();   // frag reads done before next-tile overwrite
    }

    // epilogue: +bias, cast bf16, scatter to K/Q/V [B,H,S,D] (split order k,q,v)
#pragma unroll
    for (int n = 0; n < 4; ++n) {
        const int col = n0 + wc * 64 + n * 16 + l15;   // [0,3072)
        const float bv = bias[col];
        const int which = col >> 10;
        unsigned short* outp = (which == 0) ? Ko : (which == 1 ? Qo : Vo);
        const int cm = col & 1023, h = cm >> 6, d = cm & 63;
#pragma unroll
        for (int m = 0; m < 4; ++m)
#pragma unroll
            for (int jj = 0; jj < 4; ++jj) {
                const int row = m0 + wr * 64 + m * 16 + g4 + jj;
                const int b = row >> 11, s = row & 2047;
                outp[(((size_t)(b * NH + h) * SEQ + s) << 6) + d] =
                    f2bf(acc[m][n][jj] + bv);
            }
    }
}

// ---------------------------------------------------------------------------
// Kernel 3: out = Y @ W_proj^T + b (Y already bf16; W in hi/lo -> 2-term)
// ---------------------------------------------------------------------------
__global__ __launch_bounds__(256) void gemm_proj_mfma(
    const unsigned short* __restrict__ Yb,
    const unsigned short* __restrict__ wh, const unsigned short* __restrict__ wl,
    const float* __restrict__ bias, float* __restrict__ Out) {
    __shared__ unsigned short Ah[128 * 32];
    __shared__ unsigned short Bh[128 * 32], Bl[128 * 32];

    const int t = threadIdx.x, lane = t & 63, w = t >> 6;
    const int wr = w >> 1, wc = w & 1;
    const int g8 = (lane >> 4) * 8, g4 = (lane >> 4) * 4, l15 = lane & 15;

    const int nwg = 64 * 8;                        // 512
    const int lin = blockIdx.x + gridDim.x * blockIdx.y;
    const int swz = (lin & 7) * (nwg >> 3) + (lin >> 3);
    const int m0 = (swz & 63) * 128, n0 = (swz >> 6) * 128;

    f32x4 acc[4][4] = {};

    for (int kt = 0; kt < 1024; kt += 32) {
        stage_tile(Yb, m0, kt, Ah, w, lane);
        stage_tile(wh, n0, kt, Bh, w, lane);
        stage_tile(wl, n0, kt, Bl, w, lane);
        __syncthreads();

        bf16x8 a[4], bh[4], bl[4];
#pragma unroll
        for (int m = 0; m < 4; ++m)
            a[m] = *(const bf16x8*)&Ah[(wr * 64 + m * 16 + l15) * 32 + g8];
#pragma unroll
        for (int n = 0; n < 4; ++n) {
            const int r = (wc * 64 + n * 16 + l15) * 32 + g8;
            bh[n] = *(const bf16x8*)&Bh[r];
            bl[n] = *(const bf16x8*)&Bl[r];
        }
#pragma unroll
        for (int m = 0; m < 4; ++m)
#pragma unroll
            for (int n = 0; n < 4; ++n) {
                acc[m][n] = __builtin_amdgcn_mfma_f32_16x16x32_bf16(a[m], bh[n], acc[m][n], 0, 0, 0);
                acc[m][n] = __builtin_amdgcn_mfma_f32_16x16x32_bf16(a[m], bl[n], acc[m][n], 0, 0, 0);
            }
        __syncthreads();
    }

#pragma unroll
    for (int n = 0; n < 4; ++n) {
        const int col = n0 + wc * 64 + n * 16 + l15;
        const float bv = bias[col];
#pragma unroll
        for (int m = 0; m < 4; ++m)
#pragma unroll
            for (int jj = 0; jj < 4; ++jj) {
                const int row = m0 + wr * 64 + m * 16 + g4 + jj;
                Out[(size_t)row * EMB + col] = acc[m][n][jj] + bv;
            }
    }
}

// ---------------------------------------------------------------------------
// Softmax step for one 16-row block vs a 128-KV tile (per-lane partial sums;
// exact rescale-skip when row max doesn't grow).
// ---------------------------------------------------------------------------
__device__ __forceinline__ void softmax_pwrite(
    f32x4 (&s)[8], float (&mi)[4], float (&li)[4], f32x4 (&oa)[4],
    int q0, int kvbase, bool domask, int l15, int g4,
    unsigned short (*Ps)[136], int prow0) {
    const float SCL = 0.125f * 1.44269504f;   // 1/sqrt(64) * log2(e)
#pragma unroll
    for (int n = 0; n < 8; ++n)
#pragma unroll
        for (int jj = 0; jj < 4; ++jj) {
            float v = s[n][jj] * SCL;
            if (domask && (kvbase + n * 16 + l15 > q0 + g4 + jj)) v = -1e30f;
            s[n][jj] = v;
        }
    float rm[4];
#pragma unroll
    for (int jj = 0; jj < 4; ++jj) {
        const float a0 = fmaxf(fmaxf(s[0][jj], s[1][jj]), fmaxf(s[2][jj], s[3][jj]));
        const float a1 = fmaxf(fmaxf(s[4][jj], s[5][jj]), fmaxf(s[6][jj], s[7][jj]));
        rm[jj] = fmaxf(a0, a1);
    }
#pragma unroll
    for (int msk = 1; msk < 16; msk <<= 1)
#pragma unroll
        for (int jj = 0; jj < 4; ++jj)
            rm[jj] = fmaxf(rm[jj], __shfl_xor(rm[jj], msk, 16));
    const int nogrow = (rm[0] <= mi[0]) & (rm[1] <= mi[1]) &
                       (rm[2] <= mi[2]) & (rm[3] <= mi[3]);
    if (!__all(nogrow)) {   // exact: alpha==1 when max unchanged
#pragma unroll
        for (int jj = 0; jj < 4; ++jj) {
            const float mnew = fmaxf(mi[jj], rm[jj]);
            const float alpha = exp2f(mi[jj] - mnew);
            mi[jj] = mnew;
            li[jj] *= alpha;
#pragma unroll
            for (int nd = 0; nd < 4; ++nd) oa[nd][jj] *= alpha;
        }
    }
#pragma unroll
    for (int n = 0; n < 8; ++n)
#pragma unroll
        for (int jj = 0; jj < 4; ++jj) {
            const float p = exp2f(s[n][jj] - mi[jj]);
            li[jj] += p;                         // per-lane partial row sum
            Ps[prow0 + g4 + jj][n * 16 + l15] = f2bf(p);
        }
}

// ---------------------------------------------------------------------------
// Kernel 2: causal flash attention, bf16 MFMA, work-balanced.
// Grid 512 (XCD-swizzled): block = (pair p, bh); processes q-tiles {p, 15-p}
// (128 rows each) sequentially -> exactly 17 KV-128 iterations per block.
// 4 waves; wave w owns q-rows {qt*128 + rb*64 + w*16 + 0..15}, rb = 0,1.
// LDS strides are 16B multiples (b128-clean): Ks[128][72] Vs[64][136] Ps[128][136].
// ---------------------------------------------------------------------------
__global__ __launch_bounds__(256, 2) void attn_mfma(
    const unsigned short* __restrict__ Kt, const unsigned short* __restrict__ Qt,
    const unsigned short* __restrict__ Vg, unsigned short* __restrict__ Y) {
    __shared__ unsigned short Ks[128][72];
    __shared__ unsigned short Vs[64][136];   // Vs[d][kv]
    __shared__ unsigned short Ps[128][136];  // wave-private row ranges; 128 kv cols

    const int lin = blockIdx.x;              // 0..511
    const int swz = (lin & 7) * 64 + (lin >> 3);
    const int pair = swz & 7, bh = swz >> 3;
    const int b = bh >> 4, h = bh & 15;
    const unsigned short* Qp = Qt + ((size_t)bh * SEQ << 6);
    const unsigned short* Kp = Kt + ((size_t)bh * SEQ << 6);
    const unsigned short* Vp = Vg + ((size_t)bh * SEQ << 6);

    const int t = threadIdx.x, lane = t & 63, w = t >> 6;
    const int g8 = (lane >> 4) * 8, g4 = (lane >> 4) * 4, l15 = lane & 15;

    union U8 { uint4 q; unsigned short u[8]; };
    U8 kreg[4], vreg[4];
    auto loadKV = [&](int tile) {            // 128 KV rows into regs
#pragma unroll
        for (int i = 0; i < 4; ++i) {
            const int c = t + (i << 8);      // 0..1023
            const int r = c >> 3, col = (c & 7) * 8;
            kreg[i].q = *(const uint4*)(Kp + ((size_t)tile << 13) + r * 64 + col);
            vreg[i].q = *(const uint4*)(Vp + ((size_t)tile << 13) + r * 64 + col);
        }
    };

#pragma unroll 1
    for (int ph = 0; ph < 2; ++ph) {
        const int qt = ph ? (15 - pair) : pair;
        const int ntiles = qt + 1;

        bf16x8 qf[2][2];
#pragma unroll
        for (int rb = 0; rb < 2; ++rb)
#pragma unroll
            for (int kc = 0; kc < 2; ++kc)
                qf[rb][kc] = *(const bf16x8*)(
                    Qp + ((size_t)(qt * 128 + rb * 64 + w * 16 + l15) << 6) + kc * 32 + g8);

        float m_i[2][4], l_i[2][4];
        f32x4 o_acc[2][4] = {};
#pragma unroll
        for (int rb = 0; rb < 2; ++rb)
#pragma unroll
            for (int jj = 0; jj < 4; ++jj) { m_i[rb][jj] = -1e30f; l_i[rb][jj] = 0.f; }

        loadKV(0);
#pragma unroll 1
        for (int tile = 0; tile < ntiles; ++tile) {
            __syncthreads();   // prev iteration's LDS reads done
#pragma unroll
            for (int i = 0; i < 4; ++i) {
                const int c = t + (i << 8);
                const int r = c >> 3, col = (c & 7) * 8;
                *(uint4*)&Ks[r][col] = kreg[i].q;
#pragma unroll
                for (int j = 0; j < 8; ++j) Vs[col + j][r] = vreg[i].u[j];
            }
            if (tile + 1 < ntiles) loadKV(tile + 1);   // prefetch (regs, no drain)
            __syncthreads();

            // ---- S = Q K^T for both row-blocks ----
            f32x4 s0[8] = {}, s1[8] = {};
            __builtin_amdgcn_s_setprio(1);
#pragma unroll
            for (int n = 0; n < 8; ++n) {
                const bf16x8 kf0 = *(const bf16x8*)&Ks[n * 16 + l15][g8];
                const bf16x8 kf1 = *(const bf16x8*)&Ks[n * 16 + l15][32 + g8];
                s0[n] = __builtin_amdgcn_mfma_f32_16x16x32_bf16(qf[0][0], kf0, s0[n], 0, 0, 0);
                s0[n] = __builtin_amdgcn_mfma_f32_16x16x32_bf16(qf[0][1], kf1, s0[n], 0, 0, 0);
                s1[n] = __builtin_amdgcn_mfma_f32_16x16x32_bf16(qf[1][0], kf0, s1[n], 0, 0, 0);
                s1[n] = __builtin_amdgcn_mfma_f32_16x16x32_bf16(qf[1][1], kf1, s1[n], 0, 0, 0);
            }
            __builtin_amdgcn_s_setprio(0);

            const bool domask = (tile == qt);
            const int qb = qt * 128 + w * 16, kvb = tile * 128;
            softmax_pwrite(s0, m_i[0], l_i[0], o_acc[0], qb,       kvb, domask,
                           l15, g4, Ps, w * 32);
            softmax_pwrite(s1, m_i[1], l_i[1], o_acc[1], qb + 64,  kvb, domask,
                           l15, g4, Ps, w * 32 + 16);

            // ---- O += P V (wave-local Ps; compiler inserts lgkmcnt) ----
            __builtin_amdgcn_s_setprio(1);
#pragma unroll
            for (int kc = 0; kc < 4; ++kc) {
                bf16x8 vf[4];
#pragma unroll
                for (int nd = 0; nd < 4; ++nd)
                    vf[nd] = *(const bf16x8*)&Vs[nd * 16 + l15][kc * 32 + g8];
                const bf16x8 pf0 = *(const bf16x8*)&Ps[w * 32 + l15][kc * 32 + g8];
                const bf16x8 pf1 = *(const bf16x8*)&Ps[w * 32 + 16 + l15][kc * 32 + g8];
#pragma unroll
                for (int nd = 0; nd < 4; ++nd) {
                    o_acc[0][nd] = __builtin_amdgcn_mfma_f32_16x16x32_bf16(pf0, vf[nd], o_acc[0][nd], 0, 0, 0);
                    o_acc[1][nd] = __builtin_amdgcn_mfma_f32_16x16x32_bf16(pf1, vf[nd], o_acc[1][nd], 0, 0, 0);
                }
            }
            __builtin_amdgcn_s_setprio(0);
        }

        // epilogue: reduce per-lane partial l, O/l -> bf16 -> Y[B,S,E]
#pragma unroll
        for (int rb = 0; rb < 2; ++rb)
#pragma unroll
            for (int jj = 0; jj < 4; ++jj) {
                float lv = l_i[rb][jj];
#pragma unroll
                for (int msk = 1; msk < 16; msk <<= 1)
                    lv += __shfl_xor(lv, msk, 16);
                const float inv = 1.0f / lv;
                const int srow = qt * 128 + rb * 64 + w * 16 + g4 + jj;
#pragma unroll
                for (int nd = 0; nd < 4; ++nd)
                    Y[((size_t)(b * SEQ + srow) << 10) + (h << 6) + nd * 16 + l15] =
                        f2bf(o_acc[rb][nd][jj] * inv);
            }
    }
}

// ---------------------------------------------------------------------------
extern "C" void kernel_launch(void* const* d_in, const int* in_sizes, int n_in,
                              void* d_out, int out_size, void* d_ws, size_t ws_size,
                              hipStream_t stream) {
    const float* x  = (const float*)d_in[0];
    const float* Wk = (const float*)d_in[1];
    const float* bk = (const float*)d_in[2];
    const float* Wp = (const float*)d_in[3];
    const float* bp = (const float*)d_in[4];
    float* out = (float*)d_out;

    char* ws = (char*)d_ws;
    const size_t MB = 1024 * 1024;
    unsigned short* xh  = (unsigned short*)(ws + 0 * MB);
    unsigned short* xl  = (unsigned short*)(ws + 16 * MB);
    unsigned short* wkh = (unsigned short*)(ws + 32 * MB);
    unsigned short* wkl = (unsigned short*)(ws + 38 * MB);
    unsigned short* wph = (unsigned short*)(ws + 44 * MB);
    unsigned short* wpl = (unsigned short*)(ws + 46 * MB);
    unsigned short* Ko  = (unsigned short*)(ws + 48 * MB);
    unsigned short* Qo  = (unsigned short*)(ws + 64 * MB);
    unsigned short* Vo  = (unsigned short*)(ws + 80 * MB);
    unsigned short* Yo  = (unsigned short*)(ws + 96 * MB);   // 112 MiB total

    split_bf16<<<512, 256, 0, stream>>>(x,  xh,  xl,  (BATCH * SEQ * EMB) / 4);
    split_bf16<<<256, 256, 0, stream>>>(Wk, wkh, wkl, (3 * EMB * EMB) / 4);
    split_bf16<<<128, 256, 0, stream>>>(Wp, wph, wpl, (EMB * EMB) / 4);

    gemm_qkv_mfma<<<dim3(MROWS / 128, 3072 / 128), 256, 0, stream>>>(
        xh, xl, wkh, wkl, bk, Ko, Qo, Vo);
    attn_mfma<<<512, 256, 0, stream>>>(Ko, Qo, Vo, Yo);
    gemm_proj_mfma<<<dim3(MROWS / 128, EMB / 128), 256, 0, stream>>>(
        Yo, wph, wpl, bp, out);
}

// Round 6
// 328.696 us; speedup vs baseline: 7.4666x; 1.3949x over previous
//
#include <hip/hip_runtime.h>
#include <cstddef>
#include <cstdint>

#define EMB 1024
#define NH 16
#define HD 64
#define BATCH 4
#define SEQ 2048
#define MROWS (BATCH * SEQ)   // 8192

typedef __attribute__((ext_vector_type(8))) short bf16x8;   // 8 bf16 in 4 VGPRs
typedef __attribute__((ext_vector_type(4))) float f32x4;    // MFMA C/D

__device__ __forceinline__ float bf2f(unsigned short u) {
    union { unsigned int i; float f; } c; c.i = ((unsigned int)u) << 16; return c.f;
}
__device__ __forceinline__ unsigned short f2bf(float f) {   // RNE
    union { float f; unsigned int i; } c; c.f = f;
    return (unsigned short)((c.i + 0x7FFFu + ((c.i >> 16) & 1u)) >> 16);
}

// async global->LDS, 16B per lane. LDS dest must be wave-uniform base; HW adds lane*16.
#define GLOAD_LDS16(gp, lp) __builtin_amdgcn_global_load_lds(                  \
    (const __attribute__((address_space(1))) void*)(gp),                       \
    (__attribute__((address_space(3))) void*)(lp), 16, 0, 0)

// ---------------------------------------------------------------------------
// fp32 -> bf16 (RNE), vectorized
// ---------------------------------------------------------------------------
__global__ __launch_bounds__(256) void cvt_bf16(const float* __restrict__ src,
                                                unsigned short* __restrict__ dst,
                                                int n4) {
    const int stride = gridDim.x * blockDim.x;
    for (int i = blockIdx.x * blockDim.x + threadIdx.x; i < n4; i += stride) {
        const float4 v = ((const float4*)src)[i];
        ushort4 h;
        h.x = f2bf(v.x); h.y = f2bf(v.y); h.z = f2bf(v.z); h.w = f2bf(v.w);
        ((ushort4*)dst)[i] = h;
    }
}

// ---------------------------------------------------------------------------
// Stage one 128x32 bf16 tile (linear [128][32]) via global_load_lds.
// ---------------------------------------------------------------------------
__device__ __forceinline__ void stage_tile(const unsigned short* __restrict__ src,
                                           int row0, int kt,
                                           unsigned short* lds, int wave, int lane) {
#pragma unroll
    for (int i = 0; i < 2; ++i) {
        const int c = wave * 2 + i;
        const int r = c * 16 + (lane >> 2);
        const int kq = (lane & 3) * 8;
        GLOAD_LDS16(src + (size_t)(row0 + r) * 1024 + kt + kq, lds + c * 512);
    }
}

// ---------------------------------------------------------------------------
// Kernel 1: kqv = x @ W^T + b, plain bf16 MFMA (K/Q/V stored bf16 anyway).
// 128x128 tile, 4 waves (2x2), 4x4 16x16 frags per wave.
// ---------------------------------------------------------------------------
__global__ __launch_bounds__(256) void gemm_qkv_mfma(
    const unsigned short* __restrict__ xh, const unsigned short* __restrict__ wh,
    const float* __restrict__ bias,
    unsigned short* __restrict__ Ko, unsigned short* __restrict__ Qo,
    unsigned short* __restrict__ Vo) {
    __shared__ unsigned short Ah[128 * 32];
    __shared__ unsigned short Bh[128 * 32];

    const int t = threadIdx.x, lane = t & 63, w = t >> 6;
    const int wr = w >> 1, wc = w & 1;
    const int g8 = (lane >> 4) * 8, g4 = (lane >> 4) * 4, l15 = lane & 15;

    const int nwg = 64 * 24;                       // 1536, %8 == 0
    const int lin = blockIdx.x + gridDim.x * blockIdx.y;
    const int swz = (lin & 7) * (nwg >> 3) + (lin >> 3);
    const int m0 = (swz & 63) * 128, n0 = (swz >> 6) * 128;

    f32x4 acc[4][4] = {};

    for (int kt = 0; kt < 1024; kt += 32) {
        stage_tile(xh, m0, kt, Ah, w, lane);
        stage_tile(wh, n0, kt, Bh, w, lane);
        __syncthreads();   // drains vmcnt -> staged tiles visible

        bf16x8 a[4], bb[4];
#pragma unroll
        for (int m = 0; m < 4; ++m)
            a[m] = *(const bf16x8*)&Ah[(wr * 64 + m * 16 + l15) * 32 + g8];
#pragma unroll
        for (int n = 0; n < 4; ++n)
            bb[n] = *(const bf16x8*)&Bh[(wc * 64 + n * 16 + l15) * 32 + g8];
#pragma unroll
        for (int m = 0; m < 4; ++m)
#pragma unroll
            for (int n = 0; n < 4; ++n)
                acc[m][n] = __builtin_amdgcn_mfma_f32_16x16x32_bf16(a[m], bb[n], acc[m][n], 0, 0, 0);
        __syncthreads();   // frag reads done before next-tile overwrite
    }

    // epilogue: +bias, cast bf16, scatter to K/Q/V [B,H,S,D] (split order k,q,v)
#pragma unroll
    for (int n = 0; n < 4; ++n) {
        const int col = n0 + wc * 64 + n * 16 + l15;   // [0,3072)
        const float bv = bias[col];
        const int which = col >> 10;
        unsigned short* outp = (which == 0) ? Ko : (which == 1 ? Qo : Vo);
        const int cm = col & 1023, h = cm >> 6, d = cm & 63;
#pragma unroll
        for (int m = 0; m < 4; ++m)
#pragma unroll
            for (int jj = 0; jj < 4; ++jj) {
                const int row = m0 + wr * 64 + m * 16 + g4 + jj;
                const int b = row >> 11, s = row & 2047;
                outp[(((size_t)(b * NH + h) * SEQ + s) << 6) + d] =
                    f2bf(acc[m][n][jj] + bv);
            }
    }
}

// ---------------------------------------------------------------------------
// Kernel 3: out = Y @ W_proj^T + b, plain bf16 MFMA, fp32 out
// ---------------------------------------------------------------------------
__global__ __launch_bounds__(256) void gemm_proj_mfma(
    const unsigned short* __restrict__ Yb, const unsigned short* __restrict__ wh,
    const float* __restrict__ bias, float* __restrict__ Out) {
    __shared__ unsigned short Ah[128 * 32];
    __shared__ unsigned short Bh[128 * 32];

    const int t = threadIdx.x, lane = t & 63, w = t >> 6;
    const int wr = w >> 1, wc = w & 1;
    const int g8 = (lane >> 4) * 8, g4 = (lane >> 4) * 4, l15 = lane & 15;

    const int nwg = 64 * 8;                        // 512
    const int lin = blockIdx.x + gridDim.x * blockIdx.y;
    const int swz = (lin & 7) * (nwg >> 3) + (lin >> 3);
    const int m0 = (swz & 63) * 128, n0 = (swz >> 6) * 128;

    f32x4 acc[4][4] = {};

    for (int kt = 0; kt < 1024; kt += 32) {
        stage_tile(Yb, m0, kt, Ah, w, lane);
        stage_tile(wh, n0, kt, Bh, w, lane);
        __syncthreads();

        bf16x8 a[4], bb[4];
#pragma unroll
        for (int m = 0; m < 4; ++m)
            a[m] = *(const bf16x8*)&Ah[(wr * 64 + m * 16 + l15) * 32 + g8];
#pragma unroll
        for (int n = 0; n < 4; ++n)
            bb[n] = *(const bf16x8*)&Bh[(wc * 64 + n * 16 + l15) * 32 + g8];
#pragma unroll
        for (int m = 0; m < 4; ++m)
#pragma unroll
            for (int n = 0; n < 4; ++n)
                acc[m][n] = __builtin_amdgcn_mfma_f32_16x16x32_bf16(a[m], bb[n], acc[m][n], 0, 0, 0);
        __syncthreads();
    }

#pragma unroll
    for (int n = 0; n < 4; ++n) {
        const int col = n0 + wc * 64 + n * 16 + l15;
        const float bv = bias[col];
#pragma unroll
        for (int m = 0; m < 4; ++m)
#pragma unroll
            for (int jj = 0; jj < 4; ++jj) {
                const int row = m0 + wr * 64 + m * 16 + g4 + jj;
                Out[(size_t)row * EMB + col] = acc[m][n][jj] + bv;
            }
    }
}

// ---------------------------------------------------------------------------
// Softmax step for one 16-row block vs a 128-KV tile (per-lane partial sums;
// exact rescale-skip when row max doesn't grow).
// ---------------------------------------------------------------------------
__device__ __forceinline__ void softmax_pwrite(
    f32x4 (&s)[8], float (&mi)[4], float (&li)[4], f32x4 (&oa)[4],
    int q0, int kvbase, bool domask, int l15, int g4,
    unsigned short (*Ps)[136], int prow0) {
    const float SCL = 0.125f * 1.44269504f;   // 1/sqrt(64) * log2(e)
#pragma unroll
    for (int n = 0; n < 8; ++n)
#pragma unroll
        for (int jj = 0; jj < 4; ++jj) {
            float v = s[n][jj] * SCL;
            if (domask && (kvbase + n * 16 + l15 > q0 + g4 + jj)) v = -1e30f;
            s[n][jj] = v;
        }
    float rm[4];
#pragma unroll
    for (int jj = 0; jj < 4; ++jj) {
        const float a0 = fmaxf(fmaxf(s[0][jj], s[1][jj]), fmaxf(s[2][jj], s[3][jj]));
        const float a1 = fmaxf(fmaxf(s[4][jj], s[5][jj]), fmaxf(s[6][jj], s[7][jj]));
        rm[jj] = fmaxf(a0, a1);
    }
#pragma unroll
    for (int msk = 1; msk < 16; msk <<= 1)
#pragma unroll
        for (int jj = 0; jj < 4; ++jj)
            rm[jj] = fmaxf(rm[jj], __shfl_xor(rm[jj], msk, 16));
    const int nogrow = (rm[0] <= mi[0]) & (rm[1] <= mi[1]) &
                       (rm[2] <= mi[2]) & (rm[3] <= mi[3]);
    if (!__all(nogrow)) {   // exact: alpha==1 when max unchanged
#pragma unroll
        for (int jj = 0; jj < 4; ++jj) {
            const float mnew = fmaxf(mi[jj], rm[jj]);
            const float alpha = exp2f(mi[jj] - mnew);
            mi[jj] = mnew;
            li[jj] *= alpha;
#pragma unroll
            for (int nd = 0; nd < 4; ++nd) oa[nd][jj] *= alpha;
        }
    }
#pragma unroll
    for (int n = 0; n < 8; ++n)
#pragma unroll
        for (int jj = 0; jj < 4; ++jj) {
            const float p = exp2f(s[n][jj] - mi[jj]);
            li[jj] += p;                         // per-lane partial row sum
            Ps[prow0 + g4 + jj][n * 16 + l15] = f2bf(p);
        }
}

// ---------------------------------------------------------------------------
// Kernel 2: causal flash attention, bf16 MFMA, work-balanced.
// Grid 512 (XCD-swizzled): block = (pair p, bh); processes q-tiles {p, 15-p}
// (128 rows each) sequentially -> exactly 17 KV-128 iterations per block.
// 4 waves; wave w owns q-rows {qt*128 + rb*64 + w*16 + 0..15}, rb = 0,1.
// Vs uses XOR swizzle (phys kv = kv ^ (d & 56)): transpose-write 16-way -> 2-way.
// ---------------------------------------------------------------------------
__global__ __launch_bounds__(256, 2) void attn_mfma(
    const unsigned short* __restrict__ Kt, const unsigned short* __restrict__ Qt,
    const unsigned short* __restrict__ Vg, unsigned short* __restrict__ Y) {
    __shared__ unsigned short Ks[128][72];
    __shared__ unsigned short Vs[64][136];   // Vs[d][kv ^ (d&56)]
    __shared__ unsigned short Ps[128][136];  // wave-private row ranges; 128 kv cols

    const int lin = blockIdx.x;              // 0..511
    const int swz = (lin & 7) * 64 + (lin >> 3);
    const int pair = swz & 7, bh = swz >> 3;
    const int b = bh >> 4, h = bh & 15;
    const unsigned short* Qp = Qt + ((size_t)bh * SEQ << 6);
    const unsigned short* Kp = Kt + ((size_t)bh * SEQ << 6);
    const unsigned short* Vp = Vg + ((size_t)bh * SEQ << 6);

    const int t = threadIdx.x, lane = t & 63, w = t >> 6;
    const int g8 = (lane >> 4) * 8, g4 = (lane >> 4) * 4, l15 = lane & 15;

    union U8 { uint4 q; unsigned short u[8]; };
    U8 kreg[4], vreg[4];
    auto loadKV = [&](int tile) {            // 128 KV rows into regs
#pragma unroll
        for (int i = 0; i < 4; ++i) {
            const int c = t + (i << 8);      // 0..1023
            const int r = c >> 3, col = (c & 7) * 8;
            kreg[i].q = *(const uint4*)(Kp + ((size_t)tile << 13) + r * 64 + col);
            vreg[i].q = *(const uint4*)(Vp + ((size_t)tile << 13) + r * 64 + col);
        }
    };

#pragma unroll 1
    for (int ph = 0; ph < 2; ++ph) {
        const int qt = ph ? (15 - pair) : pair;
        const int ntiles = qt + 1;

        bf16x8 qf[2][2];
#pragma unroll
        for (int rb = 0; rb < 2; ++rb)
#pragma unroll
            for (int kc = 0; kc < 2; ++kc)
                qf[rb][kc] = *(const bf16x8*)(
                    Qp + ((size_t)(qt * 128 + rb * 64 + w * 16 + l15) << 6) + kc * 32 + g8);

        float m_i[2][4], l_i[2][4];
        f32x4 o_acc[2][4] = {};
#pragma unroll
        for (int rb = 0; rb < 2; ++rb)
#pragma unroll
            for (int jj = 0; jj < 4; ++jj) { m_i[rb][jj] = -1e30f; l_i[rb][jj] = 0.f; }

        loadKV(0);
#pragma unroll 1
        for (int tile = 0; tile < ntiles; ++tile) {
            __syncthreads();   // prev iteration's LDS reads done
#pragma unroll
            for (int i = 0; i < 4; ++i) {
                const int c = t + (i << 8);
                const int r = c >> 3, col = (c & 7) * 8;
                *(uint4*)&Ks[r][col] = kreg[i].q;
#pragma unroll
                for (int j = 0; j < 8; ++j) {
                    const int d = col + j;
                    Vs[d][r ^ (d & 56)] = vreg[i].u[j];
                }
            }
            if (tile + 1 < ntiles) loadKV(tile + 1);   // prefetch (regs, no drain)
            __syncthreads();

            // ---- S = Q K^T for both row-blocks ----
            f32x4 s0[8] = {}, s1[8] = {};
            __builtin_amdgcn_s_setprio(1);
#pragma unroll
            for (int n = 0; n < 8; ++n) {
                const bf16x8 kf0 = *(const bf16x8*)&Ks[n * 16 + l15][g8];
                const bf16x8 kf1 = *(const bf16x8*)&Ks[n * 16 + l15][32 + g8];
                s0[n] = __builtin_amdgcn_mfma_f32_16x16x32_bf16(qf[0][0], kf0, s0[n], 0, 0, 0);
                s0[n] = __builtin_amdgcn_mfma_f32_16x16x32_bf16(qf[0][1], kf1, s0[n], 0, 0, 0);
                s1[n] = __builtin_amdgcn_mfma_f32_16x16x32_bf16(qf[1][0], kf0, s1[n], 0, 0, 0);
                s1[n] = __builtin_amdgcn_mfma_f32_16x16x32_bf16(qf[1][1], kf1, s1[n], 0, 0, 0);
            }
            __builtin_amdgcn_s_setprio(0);

            const bool domask = (tile == qt);
            const int qb = qt * 128 + w * 16, kvb = tile * 128;
            softmax_pwrite(s0, m_i[0], l_i[0], o_acc[0], qb,       kvb, domask,
                           l15, g4, Ps, w * 32);
            softmax_pwrite(s1, m_i[1], l_i[1], o_acc[1], qb + 64,  kvb, domask,
                           l15, g4, Ps, w * 32 + 16);

            // ---- O += P V (wave-local Ps; compiler inserts lgkmcnt) ----
            __builtin_amdgcn_s_setprio(1);
#pragma unroll
            for (int kc = 0; kc < 4; ++kc) {
                bf16x8 vf[4];
#pragma unroll
                for (int nd = 0; nd < 4; ++nd) {
                    const int d = nd * 16 + l15;
                    vf[nd] = *(const bf16x8*)&Vs[d][(kc * 32 + g8) ^ (d & 56)];
                }
                const bf16x8 pf0 = *(const bf16x8*)&Ps[w * 32 + l15][kc * 32 + g8];
                const bf16x8 pf1 = *(const bf16x8*)&Ps[w * 32 + 16 + l15][kc * 32 + g8];
#pragma unroll
                for (int nd = 0; nd < 4; ++nd) {
                    o_acc[0][nd] = __builtin_amdgcn_mfma_f32_16x16x32_bf16(pf0, vf[nd], o_acc[0][nd], 0, 0, 0);
                    o_acc[1][nd] = __builtin_amdgcn_mfma_f32_16x16x32_bf16(pf1, vf[nd], o_acc[1][nd], 0, 0, 0);
                }
            }
            __builtin_amdgcn_s_setprio(0);
        }

        // epilogue: reduce per-lane partial l, O/l -> bf16 -> Y[B,S,E]
#pragma unroll
        for (int rb = 0; rb < 2; ++rb)
#pragma unroll
            for (int jj = 0; jj < 4; ++jj) {
                float lv = l_i[rb][jj];
#pragma unroll
                for (int msk = 1; msk < 16; msk <<= 1)
                    lv += __shfl_xor(lv, msk, 16);
                const float inv = 1.0f / lv;
                const int srow = qt * 128 + rb * 64 + w * 16 + g4 + jj;
#pragma unroll
                for (int nd = 0; nd < 4; ++nd)
                    Y[((size_t)(b * SEQ + srow) << 10) + (h << 6) + nd * 16 + l15] =
                        f2bf(o_acc[rb][nd][jj] * inv);
            }
    }
}

// ---------------------------------------------------------------------------
extern "C" void kernel_launch(void* const* d_in, const int* in_sizes, int n_in,
                              void* d_out, int out_size, void* d_ws, size_t ws_size,
                              hipStream_t stream) {
    const float* x  = (const float*)d_in[0];
    const float* Wk = (const float*)d_in[1];
    const float* bk = (const float*)d_in[2];
    const float* Wp = (const float*)d_in[3];
    const float* bp = (const float*)d_in[4];
    float* out = (float*)d_out;

    char* ws = (char*)d_ws;
    const size_t MB = 1024 * 1024;
    unsigned short* xh  = (unsigned short*)(ws + 0 * MB);
    unsigned short* wkh = (unsigned short*)(ws + 16 * MB);
    unsigned short* wph = (unsigned short*)(ws + 22 * MB);
    unsigned short* Ko  = (unsigned short*)(ws + 24 * MB);
    unsigned short* Qo  = (unsigned short*)(ws + 40 * MB);
    unsigned short* Vo  = (unsigned short*)(ws + 56 * MB);
    unsigned short* Yo  = (unsigned short*)(ws + 72 * MB);   // 88 MiB total

    cvt_bf16<<<512, 256, 0, stream>>>(x,  xh,  (BATCH * SEQ * EMB) / 4);
    cvt_bf16<<<256, 256, 0, stream>>>(Wk, wkh, (3 * EMB * EMB) / 4);
    cvt_bf16<<<128, 256, 0, stream>>>(Wp, wph, (EMB * EMB) / 4);

    gemm_qkv_mfma<<<dim3(MROWS / 128, 3072 / 128), 256, 0, stream>>>(
        xh, wkh, bk, Ko, Qo, Vo);
    attn_mfma<<<512, 256, 0, stream>>>(Ko, Qo, Vo, Yo);
    gemm_proj_mfma<<<dim3(MROWS / 128, EMB / 128), 256, 0, stream>>>(
        Yo, wph, bp, out);
}

// Round 7
// 313.700 us; speedup vs baseline: 7.8235x; 1.0478x over previous
//
#include <hip/hip_runtime.h>
#include <cstddef>
#include <cstdint>

#define EMB 1024
#define NH 16
#define HD 64
#define BATCH 4
#define SEQ 2048
#define MROWS (BATCH * SEQ)   // 8192

typedef __attribute__((ext_vector_type(8))) short bf16x8;   // 8 bf16 in 4 VGPRs
typedef __attribute__((ext_vector_type(4))) float f32x4;    // MFMA C/D

__device__ __forceinline__ unsigned short f2bf(float f) {   // RNE
    union { float f; unsigned int i; } c; c.f = f;
    return (unsigned short)((c.i + 0x7FFFu + ((c.i >> 16) & 1u)) >> 16);
}
__device__ __forceinline__ unsigned short f2bfr(float f) {  // round-half-up (cheap, no bias)
    union { float f; unsigned int i; } c; c.f = f;
    return (unsigned short)((c.i + 0x8000u) >> 16);
}

// async global->LDS, 16B per lane. LDS dest must be wave-uniform base; HW adds lane*16.
#define GLOAD_LDS16(gp, lp) __builtin_amdgcn_global_load_lds(                  \
    (const __attribute__((address_space(1))) void*)(gp),                       \
    (__attribute__((address_space(3))) void*)(lp), 16, 0, 0)

// ---------------------------------------------------------------------------
// fused fp32 -> bf16 (RNE) for x, W_kqv, W_proj in one launch
// ---------------------------------------------------------------------------
__global__ __launch_bounds__(256) void cvt_all(
    const float* __restrict__ x, const float* __restrict__ wk,
    const float* __restrict__ wp, unsigned short* __restrict__ xh,
    unsigned short* __restrict__ wkh, unsigned short* __restrict__ wph) {
    const int A = (BATCH * SEQ * EMB) / 4;
    const int B2 = (3 * EMB * EMB) / 4;
    const int C = (EMB * EMB) / 4;
    const int tot = A + B2 + C;
    const int stride = gridDim.x * blockDim.x;
    for (int i = blockIdx.x * blockDim.x + threadIdx.x; i < tot; i += stride) {
        const float* s; unsigned short* d; int j;
        if (i < A)            { s = x;  d = xh;  j = i; }
        else if (i < A + B2)  { s = wk; d = wkh; j = i - A; }
        else                  { s = wp; d = wph; j = i - A - B2; }
        const float4 v = ((const float4*)s)[j];
        ushort4 h;
        h.x = f2bf(v.x); h.y = f2bf(v.y); h.z = f2bf(v.z); h.w = f2bf(v.w);
        ((ushort4*)d)[j] = h;
    }
}

// ---------------------------------------------------------------------------
// Stage one 128x32 bf16 tile (linear [128][32]) via global_load_lds.
// ---------------------------------------------------------------------------
__device__ __forceinline__ void stage_tile(const unsigned short* __restrict__ src,
                                           int row0, int kt,
                                           unsigned short* lds, int wave, int lane) {
#pragma unroll
    for (int i = 0; i < 2; ++i) {
        const int c = wave * 2 + i;
        const int r = c * 16 + (lane >> 2);
        const int kq = (lane & 3) * 8;
        GLOAD_LDS16(src + (size_t)(row0 + r) * 1024 + kt + kq, lds + c * 512);
    }
}

// ---------------------------------------------------------------------------
// Kernel 1: kqv = x @ W^T + b, plain bf16 MFMA.
// ---------------------------------------------------------------------------
__global__ __launch_bounds__(256) void gemm_qkv_mfma(
    const unsigned short* __restrict__ xh, const unsigned short* __restrict__ wh,
    const float* __restrict__ bias,
    unsigned short* __restrict__ Ko, unsigned short* __restrict__ Qo,
    unsigned short* __restrict__ Vo) {
    __shared__ unsigned short Ah[128 * 32];
    __shared__ unsigned short Bh[128 * 32];

    const int t = threadIdx.x, lane = t & 63, w = t >> 6;
    const int wr = w >> 1, wc = w & 1;
    const int g8 = (lane >> 4) * 8, g4 = (lane >> 4) * 4, l15 = lane & 15;

    const int nwg = 64 * 24;                       // 1536, %8 == 0
    const int lin = blockIdx.x + gridDim.x * blockIdx.y;
    const int swz = (lin & 7) * (nwg >> 3) + (lin >> 3);
    const int m0 = (swz & 63) * 128, n0 = (swz >> 6) * 128;

    f32x4 acc[4][4] = {};

    for (int kt = 0; kt < 1024; kt += 32) {
        stage_tile(xh, m0, kt, Ah, w, lane);
        stage_tile(wh, n0, kt, Bh, w, lane);
        __syncthreads();

        bf16x8 a[4], bb[4];
#pragma unroll
        for (int m = 0; m < 4; ++m)
            a[m] = *(const bf16x8*)&Ah[(wr * 64 + m * 16 + l15) * 32 + g8];
#pragma unroll
        for (int n = 0; n < 4; ++n)
            bb[n] = *(const bf16x8*)&Bh[(wc * 64 + n * 16 + l15) * 32 + g8];
#pragma unroll
        for (int m = 0; m < 4; ++m)
#pragma unroll
            for (int n = 0; n < 4; ++n)
                acc[m][n] = __builtin_amdgcn_mfma_f32_16x16x32_bf16(a[m], bb[n], acc[m][n], 0, 0, 0);
        __syncthreads();
    }

#pragma unroll
    for (int n = 0; n < 4; ++n) {
        const int col = n0 + wc * 64 + n * 16 + l15;   // [0,3072)
        const float bv = bias[col];
        const int which = col >> 10;
        unsigned short* outp = (which == 0) ? Ko : (which == 1 ? Qo : Vo);
        const int cm = col & 1023, h = cm >> 6, d = cm & 63;
#pragma unroll
        for (int m = 0; m < 4; ++m)
#pragma unroll
            for (int jj = 0; jj < 4; ++jj) {
                const int row = m0 + wr * 64 + m * 16 + g4 + jj;
                const int b = row >> 11, s = row & 2047;
                outp[(((size_t)(b * NH + h) * SEQ + s) << 6) + d] =
                    f2bf(acc[m][n][jj] + bv);
            }
    }
}

// ---------------------------------------------------------------------------
// Kernel 3: out = Y @ W_proj^T + b, plain bf16 MFMA, fp32 out
// ---------------------------------------------------------------------------
__global__ __launch_bounds__(256) void gemm_proj_mfma(
    const unsigned short* __restrict__ Yb, const unsigned short* __restrict__ wh,
    const float* __restrict__ bias, float* __restrict__ Out) {
    __shared__ unsigned short Ah[128 * 32];
    __shared__ unsigned short Bh[128 * 32];

    const int t = threadIdx.x, lane = t & 63, w = t >> 6;
    const int wr = w >> 1, wc = w & 1;
    const int g8 = (lane >> 4) * 8, g4 = (lane >> 4) * 4, l15 = lane & 15;

    const int nwg = 64 * 8;                        // 512
    const int lin = blockIdx.x + gridDim.x * blockIdx.y;
    const int swz = (lin & 7) * (nwg >> 3) + (lin >> 3);
    const int m0 = (swz & 63) * 128, n0 = (swz >> 6) * 128;

    f32x4 acc[4][4] = {};

    for (int kt = 0; kt < 1024; kt += 32) {
        stage_tile(Yb, m0, kt, Ah, w, lane);
        stage_tile(wh, n0, kt, Bh, w, lane);
        __syncthreads();

        bf16x8 a[4], bb[4];
#pragma unroll
        for (int m = 0; m < 4; ++m)
            a[m] = *(const bf16x8*)&Ah[(wr * 64 + m * 16 + l15) * 32 + g8];
#pragma unroll
        for (int n = 0; n < 4; ++n)
            bb[n] = *(const bf16x8*)&Bh[(wc * 64 + n * 16 + l15) * 32 + g8];
#pragma unroll
        for (int m = 0; m < 4; ++m)
#pragma unroll
            for (int n = 0; n < 4; ++n)
                acc[m][n] = __builtin_amdgcn_mfma_f32_16x16x32_bf16(a[m], bb[n], acc[m][n], 0, 0, 0);
        __syncthreads();
    }

#pragma unroll
    for (int n = 0; n < 4; ++n) {
        const int col = n0 + wc * 64 + n * 16 + l15;
        const float bv = bias[col];
#pragma unroll
        for (int m = 0; m < 4; ++m)
#pragma unroll
            for (int jj = 0; jj < 4; ++jj) {
                const int row = m0 + wr * 64 + m * 16 + g4 + jj;
                Out[(size_t)row * EMB + col] = acc[m][n][jj] + bv;
            }
    }
}

// ---------------------------------------------------------------------------
// Kernel 2: causal flash attention, bf16 MFMA, fixed-max softmax.
// Grid 1024 (XCD-swizzled): block = (pair p, bh); q-tiles {p, 31-p} of 64 rows
// -> exactly 17 KV-128 iterations per block. 4 waves; wave w owns 16 q-rows.
// Softmax uses a FIXED max of 8 (log2-domain; inputs ~N(0,1.44), global max
// ~8.5 over 1.3e8 samples; the 2^-8 factor cancels exactly in O/l; fp32 l
// cannot overflow below logit 127). No max-tracking, no rescale, no shuffles
// in the loop. Mask applied only on the diagonal (last) tile.
// LDS 53248 B -> 3 blocks/CU; 12 waves/CU.
// ---------------------------------------------------------------------------
__global__ __launch_bounds__(256, 3) void attn_mfma(
    const unsigned short* __restrict__ Kt, const unsigned short* __restrict__ Qt,
    const unsigned short* __restrict__ Vg, unsigned short* __restrict__ Y) {
    __shared__ unsigned short Ks[128][72];
    __shared__ unsigned short Vs[64][136];   // Vs[d][kv ^ (d&56)]
    __shared__ unsigned short Ps[64][136];   // wave-private 16-row ranges

    const int lin = blockIdx.x;              // 0..1023
    const int swz = (lin & 7) * 128 + (lin >> 3);
    const int pair = swz & 15, bh = swz >> 4;
    const int b = bh >> 4, h = bh & 15;
    const unsigned short* Qp = Qt + ((size_t)bh * SEQ << 6);
    const unsigned short* Kp = Kt + ((size_t)bh * SEQ << 6);
    const unsigned short* Vp = Vg + ((size_t)bh * SEQ << 6);

    const int t = threadIdx.x, lane = t & 63, w = t >> 6;
    const int g8 = (lane >> 4) * 8, g4 = (lane >> 4) * 4, l15 = lane & 15;
    const float SCL = 0.125f * 1.44269504f;  // 1/sqrt(64) * log2(e)

    union U8 { uint4 q; unsigned short u[8]; };
    U8 kreg[4], vreg[4];
    auto loadKV = [&](int tile) {            // 128 KV rows into regs
#pragma unroll
        for (int i = 0; i < 4; ++i) {
            const int c = t + (i << 8);      // 0..1023
            const int r = c >> 3, col = (c & 7) * 8;
            kreg[i].q = *(const uint4*)(Kp + ((size_t)tile << 13) + r * 64 + col);
            vreg[i].q = *(const uint4*)(Vp + ((size_t)tile << 13) + r * 64 + col);
        }
    };

#pragma unroll 1
    for (int ph = 0; ph < 2; ++ph) {
        const int qt = ph ? (31 - pair) : pair;
        const int ntiles = (qt >> 1) + 1;
        const int q0 = qt * 64 + w * 16;

        bf16x8 qf[2];
#pragma unroll
        for (int kc = 0; kc < 2; ++kc)
            qf[kc] = *(const bf16x8*)(Qp + ((size_t)(q0 + l15) << 6) + kc * 32 + g8);

        float l_i[4] = {0.f, 0.f, 0.f, 0.f};
        f32x4 o_acc[4] = {};

        loadKV(0);
#pragma unroll 1
        for (int tile = 0; tile < ntiles; ++tile) {
            __syncthreads();   // prev iteration's LDS reads done
#pragma unroll
            for (int i = 0; i < 4; ++i) {
                const int c = t + (i << 8);
                const int r = c >> 3, col = (c & 7) * 8;
                *(uint4*)&Ks[r][col] = kreg[i].q;
#pragma unroll
                for (int j = 0; j < 8; ++j) {
                    const int d = col + j;
                    Vs[d][r ^ (d & 56)] = vreg[i].u[j];
                }
            }
            if (tile + 1 < ntiles) loadKV(tile + 1);   // prefetch (regs, no drain)
            __syncthreads();

            // ---- S = Q K^T (16 q-rows x 128 kv) ----
            f32x4 s[8] = {};
            __builtin_amdgcn_s_setprio(1);
#pragma unroll
            for (int n = 0; n < 8; ++n) {
                const bf16x8 kf0 = *(const bf16x8*)&Ks[n * 16 + l15][g8];
                const bf16x8 kf1 = *(const bf16x8*)&Ks[n * 16 + l15][32 + g8];
                s[n] = __builtin_amdgcn_mfma_f32_16x16x32_bf16(qf[0], kf0, s[n], 0, 0, 0);
                s[n] = __builtin_amdgcn_mfma_f32_16x16x32_bf16(qf[1], kf1, s[n], 0, 0, 0);
            }
            __builtin_amdgcn_s_setprio(0);

            // ---- fixed-max softmax: p = exp2(s*SCL - 8) ----
            const int kvb = tile << 7;
            auto smx = [&](bool MASK) {
#pragma unroll
                for (int n = 0; n < 8; ++n)
#pragma unroll
                    for (int jj = 0; jj < 4; ++jj) {
                        float v = fmaf(s[n][jj], SCL, -8.0f);
                        if (MASK && (kvb + n * 16 + l15 > q0 + g4 + jj)) v = -1e30f;
                        const float p = exp2f(v);
                        l_i[jj] += p;
                        Ps[w * 16 + g4 + jj][n * 16 + l15] = f2bfr(p);
                    }
            };
            if (tile == ntiles - 1) smx(true); else smx(false);

            // ---- O += P V (wave-local Ps; compiler inserts lgkmcnt) ----
            __builtin_amdgcn_s_setprio(1);
#pragma unroll
            for (int kc = 0; kc < 4; ++kc) {
                bf16x8 vf[4];
#pragma unroll
                for (int nd = 0; nd < 4; ++nd) {
                    const int d = nd * 16 + l15;
                    vf[nd] = *(const bf16x8*)&Vs[d][(kc * 32 + g8) ^ (d & 56)];
                }
                const bf16x8 pf = *(const bf16x8*)&Ps[w * 16 + l15][kc * 32 + g8];
#pragma unroll
                for (int nd = 0; nd < 4; ++nd)
                    o_acc[nd] = __builtin_amdgcn_mfma_f32_16x16x32_bf16(pf, vf[nd], o_acc[nd], 0, 0, 0);
            }
            __builtin_amdgcn_s_setprio(0);
        }

        // epilogue: reduce per-lane partial l, O/l -> bf16 -> Y[B,S,E]
#pragma unroll
        for (int jj = 0; jj < 4; ++jj) {
            float lv = l_i[jj];
#pragma unroll
            for (int msk = 1; msk < 16; msk <<= 1)
                lv += __shfl_xor(lv, msk, 16);
            const float inv = 1.0f / lv;
            const int srow = q0 + g4 + jj;
#pragma unroll
            for (int nd = 0; nd < 4; ++nd)
                Y[((size_t)(b * SEQ + srow) << 10) + (h << 6) + nd * 16 + l15] =
                    f2bf(o_acc[nd][jj] * inv);
        }
    }
}

// ---------------------------------------------------------------------------
extern "C" void kernel_launch(void* const* d_in, const int* in_sizes, int n_in,
                              void* d_out, int out_size, void* d_ws, size_t ws_size,
                              hipStream_t stream) {
    const float* x  = (const float*)d_in[0];
    const float* Wk = (const float*)d_in[1];
    const float* bk = (const float*)d_in[2];
    const float* Wp = (const float*)d_in[3];
    const float* bp = (const float*)d_in[4];
    float* out = (float*)d_out;

    char* ws = (char*)d_ws;
    const size_t MB = 1024 * 1024;
    unsigned short* xh  = (unsigned short*)(ws + 0 * MB);
    unsigned short* wkh = (unsigned short*)(ws + 16 * MB);
    unsigned short* wph = (unsigned short*)(ws + 22 * MB);
    unsigned short* Ko  = (unsigned short*)(ws + 24 * MB);
    unsigned short* Qo  = (unsigned short*)(ws + 40 * MB);
    unsigned short* Vo  = (unsigned short*)(ws + 56 * MB);
    unsigned short* Yo  = (unsigned short*)(ws + 72 * MB);   // 88 MiB total

    cvt_all<<<2048, 256, 0, stream>>>(x, Wk, Wp, xh, wkh, wph);

    gemm_qkv_mfma<<<dim3(MROWS / 128, 3072 / 128), 256, 0, stream>>>(
        xh, wkh, bk, Ko, Qo, Vo);
    attn_mfma<<<1024, 256, 0, stream>>>(Ko, Qo, Vo, Yo);
    gemm_proj_mfma<<<dim3(MROWS / 128, EMB / 128), 256, 0, stream>>>(
        Yo, wph, bp, out);
}

// Round 8
// 282.928 us; speedup vs baseline: 8.6744x; 1.1088x over previous
//
#include <hip/hip_runtime.h>
#include <cstddef>
#include <cstdint>

#define EMB 1024
#define NH 16
#define HD 64
#define BATCH 4
#define SEQ 2048
#define MROWS (BATCH * SEQ)   // 8192

typedef __attribute__((ext_vector_type(8))) short bf16x8;   // 8 bf16 in 4 VGPRs
typedef __attribute__((ext_vector_type(4))) float f32x4;    // MFMA C/D

__device__ __forceinline__ unsigned short f2bf(float f) {   // RNE
    union { float f; unsigned int i; } c; c.f = f;
    return (unsigned short)((c.i + 0x7FFFu + ((c.i >> 16) & 1u)) >> 16);
}
__device__ __forceinline__ unsigned short f2bfr(float f) {  // round-half-up (cheap)
    union { float f; unsigned int i; } c; c.f = f;
    return (unsigned short)((c.i + 0x8000u) >> 16);
}

// async global->LDS, 16B per lane. LDS dest must be wave-uniform base; HW adds lane*16.
#define GLOAD_LDS16(gp, lp) __builtin_amdgcn_global_load_lds(                  \
    (const __attribute__((address_space(1))) void*)(gp),                       \
    (__attribute__((address_space(3))) void*)(lp), 16, 0, 0)

// ---------------------------------------------------------------------------
// fused fp32 -> bf16 (RNE) for x, W_kqv, W_proj in one launch
// ---------------------------------------------------------------------------
__global__ __launch_bounds__(256) void cvt_all(
    const float* __restrict__ x, const float* __restrict__ wk,
    const float* __restrict__ wp, unsigned short* __restrict__ xh,
    unsigned short* __restrict__ wkh, unsigned short* __restrict__ wph) {
    const int A = (BATCH * SEQ * EMB) / 4;
    const int B2 = (3 * EMB * EMB) / 4;
    const int C = (EMB * EMB) / 4;
    const int tot = A + B2 + C;
    const int stride = gridDim.x * blockDim.x;
    for (int i = blockIdx.x * blockDim.x + threadIdx.x; i < tot; i += stride) {
        const float* s; unsigned short* d; int j;
        if (i < A)            { s = x;  d = xh;  j = i; }
        else if (i < A + B2)  { s = wk; d = wkh; j = i - A; }
        else                  { s = wp; d = wph; j = i - A - B2; }
        const float4 v = ((const float4*)s)[j];
        ushort4 h;
        h.x = f2bf(v.x); h.y = f2bf(v.y); h.z = f2bf(v.z); h.w = f2bf(v.w);
        ((ushort4*)d)[j] = h;
    }
}

// ---------------------------------------------------------------------------
// Stage one 128x32 bf16 tile (linear [128][32]) via global_load_lds.
// ---------------------------------------------------------------------------
__device__ __forceinline__ void stage_tile(const unsigned short* __restrict__ src,
                                           int row0, int kt,
                                           unsigned short* lds, int wave, int lane) {
#pragma unroll
    for (int i = 0; i < 2; ++i) {
        const int c = wave * 2 + i;
        const int r = c * 16 + (lane >> 2);
        const int kq = (lane & 3) * 8;
        GLOAD_LDS16(src + (size_t)(row0 + r) * 1024 + kt + kq, lds + c * 512);
    }
}

// ---------------------------------------------------------------------------
// Kernel 1: kqv = x @ W^T + b, plain bf16 MFMA.
// ---------------------------------------------------------------------------
__global__ __launch_bounds__(256) void gemm_qkv_mfma(
    const unsigned short* __restrict__ xh, const unsigned short* __restrict__ wh,
    const float* __restrict__ bias,
    unsigned short* __restrict__ Ko, unsigned short* __restrict__ Qo,
    unsigned short* __restrict__ Vo) {
    __shared__ unsigned short Ah[128 * 32];
    __shared__ unsigned short Bh[128 * 32];

    const int t = threadIdx.x, lane = t & 63, w = t >> 6;
    const int wr = w >> 1, wc = w & 1;
    const int g8 = (lane >> 4) * 8, g4 = (lane >> 4) * 4, l15 = lane & 15;

    const int nwg = 64 * 24;                       // 1536, %8 == 0
    const int lin = blockIdx.x + gridDim.x * blockIdx.y;
    const int swz = (lin & 7) * (nwg >> 3) + (lin >> 3);
    const int m0 = (swz & 63) * 128, n0 = (swz >> 6) * 128;

    f32x4 acc[4][4] = {};

    for (int kt = 0; kt < 1024; kt += 32) {
        stage_tile(xh, m0, kt, Ah, w, lane);
        stage_tile(wh, n0, kt, Bh, w, lane);
        __syncthreads();

        bf16x8 a[4], bb[4];
#pragma unroll
        for (int m = 0; m < 4; ++m)
            a[m] = *(const bf16x8*)&Ah[(wr * 64 + m * 16 + l15) * 32 + g8];
#pragma unroll
        for (int n = 0; n < 4; ++n)
            bb[n] = *(const bf16x8*)&Bh[(wc * 64 + n * 16 + l15) * 32 + g8];
#pragma unroll
        for (int m = 0; m < 4; ++m)
#pragma unroll
            for (int n = 0; n < 4; ++n)
                acc[m][n] = __builtin_amdgcn_mfma_f32_16x16x32_bf16(a[m], bb[n], acc[m][n], 0, 0, 0);
        __syncthreads();
    }

#pragma unroll
    for (int n = 0; n < 4; ++n) {
        const int col = n0 + wc * 64 + n * 16 + l15;   // [0,3072)
        const float bv = bias[col];
        const int which = col >> 10;
        unsigned short* outp = (which == 0) ? Ko : (which == 1 ? Qo : Vo);
        const int cm = col & 1023, h = cm >> 6, d = cm & 63;
#pragma unroll
        for (int m = 0; m < 4; ++m)
#pragma unroll
            for (int jj = 0; jj < 4; ++jj) {
                const int row = m0 + wr * 64 + m * 16 + g4 + jj;
                const int b = row >> 11, s = row & 2047;
                outp[(((size_t)(b * NH + h) * SEQ + s) << 6) + d] =
                    f2bf(acc[m][n][jj] + bv);
            }
    }
}

// ---------------------------------------------------------------------------
// Kernel 3: out = Y @ W_proj^T + b, plain bf16 MFMA, fp32 out
// ---------------------------------------------------------------------------
__global__ __launch_bounds__(256) void gemm_proj_mfma(
    const unsigned short* __restrict__ Yb, const unsigned short* __restrict__ wh,
    const float* __restrict__ bias, float* __restrict__ Out) {
    __shared__ unsigned short Ah[128 * 32];
    __shared__ unsigned short Bh[128 * 32];

    const int t = threadIdx.x, lane = t & 63, w = t >> 6;
    const int wr = w >> 1, wc = w & 1;
    const int g8 = (lane >> 4) * 8, g4 = (lane >> 4) * 4, l15 = lane & 15;

    const int nwg = 64 * 8;                        // 512
    const int lin = blockIdx.x + gridDim.x * blockIdx.y;
    const int swz = (lin & 7) * (nwg >> 3) + (lin >> 3);
    const int m0 = (swz & 63) * 128, n0 = (swz >> 6) * 128;

    f32x4 acc[4][4] = {};

    for (int kt = 0; kt < 1024; kt += 32) {
        stage_tile(Yb, m0, kt, Ah, w, lane);
        stage_tile(wh, n0, kt, Bh, w, lane);
        __syncthreads();

        bf16x8 a[4], bb[4];
#pragma unroll
        for (int m = 0; m < 4; ++m)
            a[m] = *(const bf16x8*)&Ah[(wr * 64 + m * 16 + l15) * 32 + g8];
#pragma unroll
        for (int n = 0; n < 4; ++n)
            bb[n] = *(const bf16x8*)&Bh[(wc * 64 + n * 16 + l15) * 32 + g8];
#pragma unroll
        for (int m = 0; m < 4; ++m)
#pragma unroll
            for (int n = 0; n < 4; ++n)
                acc[m][n] = __builtin_amdgcn_mfma_f32_16x16x32_bf16(a[m], bb[n], acc[m][n], 0, 0, 0);
        __syncthreads();
    }

#pragma unroll
    for (int n = 0; n < 4; ++n) {
        const int col = n0 + wc * 64 + n * 16 + l15;
        const float bv = bias[col];
#pragma unroll
        for (int m = 0; m < 4; ++m)
#pragma unroll
            for (int jj = 0; jj < 4; ++jj) {
                const int row = m0 + wr * 64 + m * 16 + g4 + jj;
                Out[(size_t)row * EMB + col] = acc[m][n][jj] + bv;
            }
    }
}

// ---------------------------------------------------------------------------
// Kernel 2: causal flash attention, bf16 MFMA, swapped QK^T + streaming
// fixed-max softmax.
// Grid 512 (XCD-swizzled): block = (pair p, bh); q-tiles {p, 15-p} of 128 rows
// -> exactly 17 KV-128 iterations per block; 512 blocks = 2/CU, no tail.
// 4 waves; wave w owns 32 q-rows (2 row-blocks of 16).
// Swapped S^T = mfma(K,Q): lane holds q=l15, kv=n*16+4*hi+jj -> kv consecutive
// in jj => P packs to b64 writes; row-sum is one per-lane scalar.
// Softmax streams inside the QK^T loop (fixed max -8, no cross-value dep).
// ---------------------------------------------------------------------------
__global__ __launch_bounds__(256, 2) void attn_mfma(
    const unsigned short* __restrict__ Kt, const unsigned short* __restrict__ Qt,
    const unsigned short* __restrict__ Vg, unsigned short* __restrict__ Y) {
    __shared__ unsigned short Ks[128][72];
    __shared__ unsigned short Vs[64][136];   // Vs[d][kv ^ (d&56)]
    __shared__ unsigned short Ps[128][136];  // P[q][kv], wave-private 32-row ranges

    const int lin = blockIdx.x;              // 0..511
    const int swz = (lin & 7) * 64 + (lin >> 3);
    const int pair = swz & 7, bh = swz >> 3;
    const int b = bh >> 4, h = bh & 15;
    const unsigned short* Qp = Qt + ((size_t)bh * SEQ << 6);
    const unsigned short* Kp = Kt + ((size_t)bh * SEQ << 6);
    const unsigned short* Vp = Vg + ((size_t)bh * SEQ << 6);

    const int t = threadIdx.x, lane = t & 63, w = t >> 6;
    const int hi = lane >> 4, l15 = lane & 15, g8 = hi * 8;
    const float SCL = 0.125f * 1.44269504f;  // 1/sqrt(64) * log2(e)

    union U8 { uint4 q; unsigned short u[8]; };
    U8 kreg[4], vreg[4];
    auto loadKV = [&](int tile) {            // 128 KV rows into regs
#pragma unroll
        for (int i = 0; i < 4; ++i) {
            const int c = t + (i << 8);      // 0..1023
            const int r = c >> 3, col = (c & 7) * 8;
            kreg[i].q = *(const uint4*)(Kp + ((size_t)tile << 13) + r * 64 + col);
            vreg[i].q = *(const uint4*)(Vp + ((size_t)tile << 13) + r * 64 + col);
        }
    };

#pragma unroll 1
    for (int ph = 0; ph < 2; ++ph) {
        const int qt = ph ? (15 - pair) : pair;
        const int ntiles = qt + 1;
        const int q0 = qt * 128 + w * 32;    // wave's first q-row

        // Q fragments (B-operand): rows q0+rb*16+l15
        bf16x8 qf[2][2];
#pragma unroll
        for (int rb = 0; rb < 2; ++rb)
#pragma unroll
            for (int kc = 0; kc < 2; ++kc)
                qf[rb][kc] = *(const bf16x8*)(
                    Qp + ((size_t)(q0 + rb * 16 + l15) << 6) + kc * 32 + g8);

        float lsum[2] = {0.f, 0.f};
        f32x4 o_acc[2][4] = {};

        loadKV(0);
#pragma unroll 1
        for (int tile = 0; tile < ntiles; ++tile) {
            __syncthreads();   // prev iteration's LDS reads done
#pragma unroll
            for (int i = 0; i < 4; ++i) {
                const int c = t + (i << 8);
                const int r = c >> 3, col = (c & 7) * 8;
                *(uint4*)&Ks[r][col] = kreg[i].q;
#pragma unroll
                for (int j = 0; j < 8; ++j) {
                    const int d = col + j;
                    Vs[d][r ^ (d & 56)] = vreg[i].u[j];
                }
            }
            if (tile + 1 < ntiles) loadKV(tile + 1);   // prefetch (regs, no drain)
            __syncthreads();

            const bool diag = (tile == ntiles - 1);
            const int kvb = tile << 7;

            // ---- S^T = K Q^T with streaming softmax + packed P write ----
            __builtin_amdgcn_s_setprio(1);
#pragma unroll
            for (int n = 0; n < 8; ++n) {
                const bf16x8 kf0 = *(const bf16x8*)&Ks[n * 16 + l15][g8];
                const bf16x8 kf1 = *(const bf16x8*)&Ks[n * 16 + l15][32 + g8];
                f32x4 t0 = {}, t1 = {};
                t0 = __builtin_amdgcn_mfma_f32_16x16x32_bf16(kf0, qf[0][0], t0, 0, 0, 0);
                t0 = __builtin_amdgcn_mfma_f32_16x16x32_bf16(kf1, qf[0][1], t0, 0, 0, 0);
                t1 = __builtin_amdgcn_mfma_f32_16x16x32_bf16(kf0, qf[1][0], t1, 0, 0, 0);
                t1 = __builtin_amdgcn_mfma_f32_16x16x32_bf16(kf1, qf[1][1], t1, 0, 0, 0);
#pragma unroll
                for (int rb = 0; rb < 2; ++rb) {
                    const f32x4 tt = rb ? t1 : t0;
                    const int qrow = q0 + rb * 16 + l15;
                    unsigned int pk[2];
#pragma unroll
                    for (int jp = 0; jp < 2; ++jp) {
                        float v0 = fmaf(tt[2 * jp], SCL, -8.0f);
                        float v1 = fmaf(tt[2 * jp + 1], SCL, -8.0f);
                        if (diag) {
                            const int kv = kvb + n * 16 + 4 * hi + 2 * jp;
                            if (kv > qrow)     v0 = -1e30f;
                            if (kv + 1 > qrow) v1 = -1e30f;
                        }
                        const float p0 = exp2f(v0), p1 = exp2f(v1);
                        lsum[rb] += p0 + p1;
                        pk[jp] = (unsigned int)f2bfr(p0) |
                                 ((unsigned int)f2bfr(p1) << 16);
                    }
                    *(uint2*)&Ps[w * 32 + rb * 16 + l15][n * 16 + 4 * hi] =
                        make_uint2(pk[0], pk[1]);
                }
            }

            // ---- O += P V (wave-local Ps; compiler inserts lgkmcnt) ----
#pragma unroll
            for (int kc = 0; kc < 4; ++kc) {
                bf16x8 vf[4];
#pragma unroll
                for (int nd = 0; nd < 4; ++nd) {
                    const int d = nd * 16 + l15;
                    vf[nd] = *(const bf16x8*)&Vs[d][(kc * 32 + g8) ^ (d & 56)];
                }
                const bf16x8 pf0 = *(const bf16x8*)&Ps[w * 32 + l15][kc * 32 + g8];
                const bf16x8 pf1 = *(const bf16x8*)&Ps[w * 32 + 16 + l15][kc * 32 + g8];
#pragma unroll
                for (int nd = 0; nd < 4; ++nd) {
                    o_acc[0][nd] = __builtin_amdgcn_mfma_f32_16x16x32_bf16(pf0, vf[nd], o_acc[0][nd], 0, 0, 0);
                    o_acc[1][nd] = __builtin_amdgcn_mfma_f32_16x16x32_bf16(pf1, vf[nd], o_acc[1][nd], 0, 0, 0);
                }
            }
            __builtin_amdgcn_s_setprio(0);
        }

        // epilogue: reduce l across hi-copies, O/l -> bf16 -> Y[B,S,E]
        // o_acc[rb][nd][jj] holds O[q = q0+rb*16+4*hi+jj][d = nd*16+l15]
#pragma unroll
        for (int rb = 0; rb < 2; ++rb) {
            float lv = lsum[rb];
            lv += __shfl_xor(lv, 16);
            lv += __shfl_xor(lv, 32);          // all lanes: l for q-row = l15
#pragma unroll
            for (int jj = 0; jj < 4; ++jj) {
                const float inv = 1.0f / __shfl(lv, 4 * hi + jj);
                const int srow = q0 + rb * 16 + 4 * hi + jj;
#pragma unroll
                for (int nd = 0; nd < 4; ++nd)
                    Y[((size_t)(b * SEQ + srow) << 10) + (h << 6) + nd * 16 + l15] =
                        f2bf(o_acc[rb][nd][jj] * inv);
            }
        }
    }
}

// ---------------------------------------------------------------------------
extern "C" void kernel_launch(void* const* d_in, const int* in_sizes, int n_in,
                              void* d_out, int out_size, void* d_ws, size_t ws_size,
                              hipStream_t stream) {
    const float* x  = (const float*)d_in[0];
    const float* Wk = (const float*)d_in[1];
    const float* bk = (const float*)d_in[2];
    const float* Wp = (const float*)d_in[3];
    const float* bp = (const float*)d_in[4];
    float* out = (float*)d_out;

    char* ws = (char*)d_ws;
    const size_t MB = 1024 * 1024;
    unsigned short* xh  = (unsigned short*)(ws + 0 * MB);
    unsigned short* wkh = (unsigned short*)(ws + 16 * MB);
    unsigned short* wph = (unsigned short*)(ws + 22 * MB);
    unsigned short* Ko  = (unsigned short*)(ws + 24 * MB);
    unsigned short* Qo  = (unsigned short*)(ws + 40 * MB);
    unsigned short* Vo  = (unsigned short*)(ws + 56 * MB);
    unsigned short* Yo  = (unsigned short*)(ws + 72 * MB);   // 88 MiB total

    cvt_all<<<2048, 256, 0, stream>>>(x, Wk, Wp, xh, wkh, wph);

    gemm_qkv_mfma<<<dim3(MROWS / 128, 3072 / 128), 256, 0, stream>>>(
        xh, wkh, bk, Ko, Qo, Vo);
    attn_mfma<<<512, 256, 0, stream>>>(Ko, Qo, Vo, Yo);
    gemm_proj_mfma<<<dim3(MROWS / 128, EMB / 128), 256, 0, stream>>>(
        Yo, wph, bp, out);
}